// Round 1
// 1663.374 us; speedup vs baseline: 1.6444x; 1.6444x over previous
//
#include <hip/hip_runtime.h>

// Seq2Seq GRU: B=256, S=128, T=64, I=63, H=1024. Inputs fp32, output fp32.
// All GEMMs: bf16 hi+lo 3-term split emulation (~fp32 accuracy).
// Encoder v6: persistent kernel, 128 steps.
//   NEW (ROT=1, used when ws_size permits): fence-free step protocol.
//     - h double-buffer replaced by 129 rotating 1MB buffers (write buf[s+1],
//       read buf[s]) -> consumer L2 can never hold a stale line (address is
//       first-touch) -> NO per-step buffer_inv.
//     - h stored with system-scope write-through stores (sc0 sc1); visibility
//       guaranteed by the vmcnt drain in __syncthreads -> NO per-step wbl2.
//     - group barrier = one fetch_add + single-line poll per mt-group
//       (64-line/64-lane poll scheme removed).
//     - Whh-lo / x stay L2-warm across steps (no invalidate).
//   ROT=0 fallback = round-8-proven fence+slot protocol (unchanged).

typedef unsigned short u16;
typedef unsigned int   u32;
typedef __attribute__((ext_vector_type(8))) short s8v;   // 8 x bf16 (4 VGPRs)
typedef __attribute__((ext_vector_type(4))) float f4v;   // MFMA acc
typedef __attribute__((ext_vector_type(4))) int  i4v;    // 16B copy unit

__device__ __forceinline__ float b2f(u16 u) {
    return __uint_as_float(((u32)u) << 16);
}
__device__ __forceinline__ u16 f2b(float f) {   // round-to-nearest-even
    u32 x = __float_as_uint(f);
    u32 r = x + 0x7fffu + ((x >> 16) & 1u);
    return (u16)(r >> 16);
}
__device__ __forceinline__ float sigf(float x) {
    return 1.0f / (1.0f + __expf(-x));
}
__device__ __forceinline__ f4v mfma16(s8v a, s8v b, f4v c) {
    return __builtin_amdgcn_mfma_f32_16x16x32_bf16(a, b, c, 0, 0, 0);
}

// ---------------------------------------------------------------------------
__global__ void zero_ws(i4v* __restrict__ p, int n) {
    int i = blockIdx.x * blockDim.x + threadIdx.x;
    if (i < n) { i4v z = {0, 0, 0, 0}; p[i] = z; }
}

__global__ void conv_split(const float* __restrict__ s, u16* __restrict__ hi,
                           u16* __restrict__ lo, int n) {
    int i = blockIdx.x * blockDim.x + threadIdx.x;
    int st = gridDim.x * blockDim.x;
    for (; i < n; i += st) {
        float v = s[i];
        u16 h = f2b(v);
        hi[i] = h;
        lo[i] = f2b(v - b2f(h));
    }
}

// Wih (3072 x 63 fp32) -> padded (3072 x 64) hi+lo, col 63 = 0
__global__ void conv_wih_split_pad(const float* __restrict__ s,
                                   u16* __restrict__ hi, u16* __restrict__ lo) {
    int idx = blockIdx.x * blockDim.x + threadIdx.x;
    int row = idx >> 6, col = idx & 63;
    float v = (col < 63) ? s[(size_t)row * 63 + col] : 0.f;
    u16 h = f2b(v);
    hi[idx] = h;
    lo[idx] = f2b(v - b2f(h));
}

// proj_W (63 x 1024 fp32) -> padded (64 x 1024) hi+lo, row 63 = 0
__global__ void conv_pw_split_pad(const float* __restrict__ s,
                                  u16* __restrict__ hi, u16* __restrict__ lo) {
    int idx = blockIdx.x * blockDim.x + threadIdx.x;
    float v = (idx < 63 * 1024) ? s[idx] : 0.f;
    u16 h = f2b(v);
    hi[idx] = h;
    lo[idx] = f2b(v - b2f(h));
}

// ---------------------------------------------------------------------------
// Persistent encoder. ROT=1: rotating buffers + counter barrier (fence-free).
// ROT=0: legacy double-buffer + fence/slot barrier (proven fallback).
template<int ROT>
__global__ __launch_bounds__(512, 1) void enc_persist(
    const u16* __restrict__ WhhH, const u16* __restrict__ WhhL,
    const u16* __restrict__ WihH, const u16* __restrict__ WihL,
    const float* __restrict__ bih, const float* __restrict__ bhh,
    const float* __restrict__ xenc,
    u16* __restrict__ hbuf, int* __restrict__ ep)
{
    __shared__ u16 BH[48 * 1032];      // Whh-hi slice, PERSISTENT (99.1 KB)
    __shared__ u16 BLs[2][48 * 136];   // per-k-group Whh-lo chunk, BK=128 (25.5 KB)
    __shared__ u16 WisH[48 * 72];      // Wih slice (persistent)
    __shared__ u16 WisL[48 * 72];
    __shared__ f4v red[4][3][64];      // k-group-1 partials (12.3 KB)

    if (ROT) {
        // one-time: drop any stale lines from a previous graph replay
        __builtin_amdgcn_fence(__ATOMIC_ACQUIRE, "agent");
    }

    const int tid  = threadIdx.x;
    const int lane = tid & 63;
    const int wave = tid >> 6;          // 0..7
    const int g    = wave >> 2;         // k-group: 0 -> k[0,512), 1 -> k[512,1024)
    const int wv   = wave & 3;          // m-subtile (16 rows)
    const int gtid = tid & 255;
    const int lrow = lane & 15;
    const int lk8  = lane >> 4;
    // XCD-aware swizzle: bid&7 = XCD; XCD owns a 128-col j-range.
    const int bid = blockIdx.x;
    const int y   = bid >> 3;
    const int mt  = y & 3;
    const int jt  = (bid & 7) * 8 + (y >> 2);
    const int m0 = mt * 64;
    const int j0 = jt * 16;

    int* grpCtr   = ep + mt * 16;                   // ROT: 1 ctr per mt group
    int* mySlot   = ep + (mt * 64 + jt) * 16;       // legacy slots
    int* laneSlot = ep + (mt * 64 + lane) * 16;

    // ---- one-time: BH (Whh-hi) into LDS, 512 thr x 12 i4v
    #pragma unroll
    for (int i = 0; i < 12; ++i) {
        int u = i * 512 + tid;
        int row = u >> 7, p = u & 127;
        int grow = (row >> 4) * 1024 + j0 + (row & 15);
        *(i4v*)&BH[row * 1032 + p * 8] = *(const i4v*)(WhhH + (size_t)grow * 1024 + p * 8);
    }
    // ---- one-time: Wih slice into LDS
    if (tid < 192) {
        int wr = tid >> 2, qq = tid & 3;
        int grow = (wr >> 4) * 1024 + j0 + (wr & 15);
        const u16* wpH = WihH + (size_t)grow * 64 + qq * 16;
        const u16* wpL = WihL + (size_t)grow * 64 + qq * 16;
        *(i4v*)&WisH[wr * 72 + qq * 16]     = *(const i4v*)wpH;
        *(i4v*)&WisH[wr * 72 + qq * 16 + 8] = *(const i4v*)(wpH + 8);
        *(i4v*)&WisL[wr * 72 + qq * 16]     = *(const i4v*)wpL;
        *(i4v*)&WisL[wr * 72 + qq * 16 + 8] = *(const i4v*)(wpL + 8);
    }

    const int jcol = j0 + lrow;
    const float bhr = bhh[jcol], bhz = bhh[1024 + jcol], bhn = bhh[2048 + jcol];
    const float bir = bih[jcol], biz = bih[1024 + jcol], bin = bih[2048 + jcol];

    // BL staging geometry: per-group 256 threads cover 48x128 u16 = 3 i4v each
    int blrow[3], blp[3], blgrow[3];
    #pragma unroll
    for (int i = 0; i < 3; ++i) {
        int u = i * 256 + gtid;
        blrow[i] = u >> 4;
        blp[i]   = u & 15;
        blgrow[i] = (blrow[i] >> 4) * 1024 + j0 + (blrow[i] & 15);
    }

    const size_t arow = (size_t)(m0 + wv * 16 + lrow) * 1024 + lk8 * 8;
    const int kbase = g * 512;
    const float* xrow = xenc + (size_t)(m0 + wv * 16 + lrow) * 8064;

    float hprev[4] = {0.f, 0.f, 0.f, 0.f};

    // ---- initial prefetch: BL chunk 0 + x(s=0)
    i4v stgL[3];
    #pragma unroll
    for (int i = 0; i < 3; ++i)
        stgL[i] = *(const i4v*)(WhhL + (size_t)blgrow[i] * 1024 + kbase + blp[i] * 8);
    float xf[16];
    if (g == 0) {
        #pragma unroll
        for (int ks = 0; ks < 2; ++ks)
            #pragma unroll
            for (int j = 0; j < 8; ++j) {
                int col = ks * 32 + lk8 * 8 + j;
                xf[ks * 8 + j] = (col < 63) ? xrow[col] : 0.f;
            }
    }

    __syncthreads();   // BH / Wis ready

    for (int s = 0; s < 128; ++s) {
        const u16 *hinH, *hinL; u16 *houtH, *houtL;
        if (ROT) {
            // rotating: read buf[s], write buf[s+1]; each 1MB = hi(256K u16)+lo
            hinH  = hbuf + (size_t)s * 524288;        hinL  = hinH + 262144;
            houtH = hbuf + (size_t)(s + 1) * 524288;  houtL = houtH + 262144;
        } else if (s & 1) {
            hinH = hbuf + 524288; hinL = hbuf + 786432;
            houtH = hbuf;         houtL = hbuf + 262144;
        } else {
            hinH = hbuf;          hinL = hbuf + 262144;
            houtH = hbuf + 524288; houtL = hbuf + 786432;
        }

        // ---- write prefetched BL chunk 0
        #pragma unroll
        for (int i = 0; i < 3; ++i)
            *(i4v*)&BLs[g][blrow[i] * 136 + blp[i] * 8] = stgL[i];
        __syncthreads();

        f4v acc_r  = {0.f, 0.f, 0.f, 0.f};
        f4v acc_z  = {0.f, 0.f, 0.f, 0.f};
        f4v acc_gn = {0.f, 0.f, 0.f, 0.f};
        f4v acc_hn = {0.f, 0.f, 0.f, 0.f};

        // ---- gi (group 0): x @ Wih^T, K=64 padded, 3-term split
        if (g == 0) {
            #pragma unroll
            for (int ks = 0; ks < 2; ++ks) {
                union { u16 a[8]; s8v v; } xh, xl;
                #pragma unroll
                for (int j = 0; j < 8; ++j) {
                    float v = xf[ks * 8 + j];
                    u16 hh = f2b(v);
                    xh.a[j] = hh;
                    xl.a[j] = f2b(v - b2f(hh));
                }
                int ao = ks * 32 + lk8 * 8;
                s8v brh = *(const s8v*)&WisH[(lrow) * 72 + ao];
                s8v brl = *(const s8v*)&WisL[(lrow) * 72 + ao];
                s8v bzh = *(const s8v*)&WisH[(16 + lrow) * 72 + ao];
                s8v bzl = *(const s8v*)&WisL[(16 + lrow) * 72 + ao];
                s8v bnh = *(const s8v*)&WisH[(32 + lrow) * 72 + ao];
                s8v bnl = *(const s8v*)&WisL[(32 + lrow) * 72 + ao];
                acc_r  = mfma16(xh.v, brh, acc_r);
                acc_r  = mfma16(xh.v, brl, acc_r);
                acc_r  = mfma16(xl.v, brh, acc_r);
                acc_z  = mfma16(xh.v, bzh, acc_z);
                acc_z  = mfma16(xh.v, bzl, acc_z);
                acc_z  = mfma16(xl.v, bzh, acc_z);
                acc_gn = mfma16(xh.v, bnh, acc_gn);
                acc_gn = mfma16(xh.v, bnl, acc_gn);
                acc_gn = mfma16(xl.v, bnh, acc_gn);
            }
        }

        const u16* hp = hinH + arow;
        const u16* lp = hinL + arow;

        // ---- K loop: 4 chunks of BK=128 per k-group
        for (int c = 0; c < 4; ++c) {
            if (c < 3) {   // prefetch next BL chunk into regs
                #pragma unroll
                for (int i = 0; i < 3; ++i)
                    stgL[i] = *(const i4v*)(WhhL + (size_t)blgrow[i] * 1024 +
                                            kbase + (c + 1) * 128 + blp[i] * 8);
            }
            #pragma unroll
            for (int ks = 0; ks < 4; ++ks) {
                int kk = kbase + c * 128 + ks * 32;
                int bh = kk + lk8 * 8;            // BH col (absolute k)
                int bl = ks * 32 + lk8 * 8;       // BL col (chunk-local)
                s8v ahi = *(const s8v*)(hp + kk);
                s8v alo = *(const s8v*)(lp + kk);
                s8v brh = *(const s8v*)&BH[(lrow) * 1032 + bh];
                s8v brl = *(const s8v*)&BLs[g][(lrow) * 136 + bl];
                s8v bzh = *(const s8v*)&BH[(16 + lrow) * 1032 + bh];
                s8v bzl = *(const s8v*)&BLs[g][(16 + lrow) * 136 + bl];
                s8v bnh = *(const s8v*)&BH[(32 + lrow) * 1032 + bh];
                s8v bnl = *(const s8v*)&BLs[g][(32 + lrow) * 136 + bl];
                acc_r  = mfma16(ahi, brh, acc_r);
                acc_r  = mfma16(ahi, brl, acc_r);
                acc_r  = mfma16(alo, brh, acc_r);
                acc_z  = mfma16(ahi, bzh, acc_z);
                acc_z  = mfma16(ahi, bzl, acc_z);
                acc_z  = mfma16(alo, bzh, acc_z);
                acc_hn = mfma16(ahi, bnh, acc_hn);
                acc_hn = mfma16(ahi, bnl, acc_hn);
                acc_hn = mfma16(alo, bnh, acc_hn);
            }
            __syncthreads();
            if (c < 3) {
                #pragma unroll
                for (int i = 0; i < 3; ++i)
                    *(i4v*)&BLs[g][blrow[i] * 136 + blp[i] * 8] = stgL[i];
                __syncthreads();
            }
        }

        // ---- reduce k-group partials, gate epilogue (group 0)
        if (g == 1) {
            red[wv][0][lane] = acc_r;
            red[wv][1][lane] = acc_z;
            red[wv][2][lane] = acc_hn;
        }
        __syncthreads();
        if (g == 0) {
            f4v r1 = red[wv][0][lane];
            f4v z1 = red[wv][1][lane];
            f4v n1 = red[wv][2][lane];
            #pragma unroll
            for (int reg = 0; reg < 4; ++reg) {
                int brow = m0 + wv * 16 + lk8 * 4 + reg;
                float rr = sigf(acc_r[reg] + r1[reg] + bir + bhr);
                float zz = sigf(acc_z[reg] + z1[reg] + biz + bhz);
                float nn = tanhf(acc_gn[reg] + bin + rr * (acc_hn[reg] + n1[reg] + bhn));
                float h = (1.f - zz) * nn + zz * hprev[reg];
                u16 hh = f2b(h);
                u16 ll = f2b(h - b2f(hh));
                hprev[reg] = b2f(hh) + b2f(ll);
                size_t off = (size_t)brow * 1024 + jcol;
                if (ROT) {
                    // write-through (sc0 sc1): visible at coherence point once
                    // this wave's vmcnt drains at the barrier below -> no wbl2.
                    __hip_atomic_store(&houtH[off], hh, __ATOMIC_RELAXED,
                                       __HIP_MEMORY_SCOPE_SYSTEM);
                    __hip_atomic_store(&houtL[off], ll, __ATOMIC_RELAXED,
                                       __HIP_MEMORY_SCOPE_SYSTEM);
                } else {
                    houtH[off] = hh;
                    houtL[off] = ll;
                }
            }
        }

        // ---- barrier
        __syncthreads();   // drains h stores (vmcnt 0 per wave)
        if (ROT) {
            if (tid == 0)
                __hip_atomic_fetch_add(grpCtr, 1, __ATOMIC_RELAXED,
                                       __HIP_MEMORY_SCOPE_SYSTEM);
        } else if (tid == 0) {
            __builtin_amdgcn_fence(__ATOMIC_RELEASE, "agent");   // wbl2
            __hip_atomic_store(mySlot, s + 1, __ATOMIC_RELAXED,
                               __HIP_MEMORY_SCOPE_AGENT);
        }
        // prefetch next step's BL chunk0 + x (immutable: no fence ordering needed)
        #pragma unroll
        for (int i = 0; i < 3; ++i)
            stgL[i] = *(const i4v*)(WhhL + (size_t)blgrow[i] * 1024 + kbase + blp[i] * 8);
        if (g == 0) {
            int sn = (s < 127) ? s + 1 : 127;
            const float* xr = xrow + sn * 63;
            #pragma unroll
            for (int ks = 0; ks < 2; ++ks)
                #pragma unroll
                for (int j = 0; j < 8; ++j) {
                    int col = ks * 32 + lk8 * 8 + j;
                    xf[ks * 8 + j] = (col < 63) ? xr[col] : 0.f;
                }
        }
        if (ROT) {
            // single-line poll: ctr >= 64*(s+1) <=> all 64 group blocks posted
            // step s (max skew is 1 step by induction). No acquire fence:
            // next step's h addresses are first-touch -> no stale L2 lines.
            if (wave == 0 && lane == 0) {
                int tgt = (s + 1) << 6;
                while (__hip_atomic_load(grpCtr, __ATOMIC_RELAXED,
                                         __HIP_MEMORY_SCOPE_SYSTEM) < tgt)
                    __builtin_amdgcn_s_sleep(1);
            }
        } else if (wave == 0) {
            for (;;) {
                int v = __hip_atomic_load(laneSlot, __ATOMIC_RELAXED,
                                          __HIP_MEMORY_SCOPE_AGENT);
                if (__all(v >= s + 1)) break;
                __builtin_amdgcn_s_sleep(2);
            }
            __builtin_amdgcn_fence(__ATOMIC_ACQUIRE, "agent");   // inv
        }
        __syncthreads();
    }
}

// ---------------------------------------------------------------------------
// gh_dec = enc_h @ dec_Whh^T + dec_bhh (fp32 out).
__global__ __launch_bounds__(256, 1) void gru_gemm1(
    const u16* __restrict__ WhhH, const u16* __restrict__ WhhL,
    const float* __restrict__ bhh,
    const u16* __restrict__ hin_hi, const u16* __restrict__ hin_lo,
    float* __restrict__ gh_out)
{
    __shared__ u16 WbH[48 * 264];
    __shared__ u16 WbL[48 * 264];

    const int tid  = threadIdx.x;
    const int lane = tid & 63;
    const int wave = tid >> 6;
    const int lrow = lane & 15;
    const int lk8  = lane >> 4;
    const int mt = blockIdx.x & 3;
    const int jt = blockIdx.x >> 2;
    const int m0 = mt * 64;
    const int j0 = jt * 16;

    f4v acc_r  = {0.f, 0.f, 0.f, 0.f};
    f4v acc_z  = {0.f, 0.f, 0.f, 0.f};
    f4v acc_hn = {0.f, 0.f, 0.f, 0.f};

    i4v stgH[6], stgL[6];
    #pragma unroll
    for (int i = 0; i < 6; ++i) {
        int c16 = i * 256 + tid;
        int row = c16 >> 5, p16 = c16 & 31;
        int grow = (row >> 4) * 1024 + j0 + (row & 15);
        size_t off = (size_t)grow * 1024 + p16 * 8;
        stgH[i] = *(const i4v*)(WhhH + off);
        stgL[i] = *(const i4v*)(WhhL + off);
    }
    #pragma unroll
    for (int i = 0; i < 6; ++i) {
        int c16 = i * 256 + tid;
        int row = c16 >> 5, p16 = c16 & 31;
        *(i4v*)&WbH[row * 264 + p16 * 8] = stgH[i];
        *(i4v*)&WbL[row * 264 + p16 * 8] = stgL[i];
    }
    __syncthreads();

    const size_t arow = (size_t)(m0 + wave * 16 + lrow) * 1024 + lk8 * 8;
    const u16* hp = hin_hi + arow;
    const u16* lp = hin_lo + arow;

    for (int c = 0; c < 4; ++c) {
        if (c < 3) {
            #pragma unroll
            for (int i = 0; i < 6; ++i) {
                int c16 = i * 256 + tid;
                int row = c16 >> 5, p16 = c16 & 31;
                int grow = (row >> 4) * 1024 + j0 + (row & 15);
                size_t off = (size_t)grow * 1024 + (c + 1) * 256 + p16 * 8;
                stgH[i] = *(const i4v*)(WhhH + off);
                stgL[i] = *(const i4v*)(WhhL + off);
            }
        }
        #pragma unroll
        for (int ks = 0; ks < 8; ++ks) {
            int kk = c * 256 + ks * 32;
            int bo = ks * 32 + lk8 * 8;
            s8v ahi = *(const s8v*)(hp + kk);
            s8v alo = *(const s8v*)(lp + kk);
            s8v brh = *(const s8v*)&WbH[(lrow) * 264 + bo];
            s8v brl = *(const s8v*)&WbL[(lrow) * 264 + bo];
            s8v bzh = *(const s8v*)&WbH[(16 + lrow) * 264 + bo];
            s8v bzl = *(const s8v*)&WbL[(16 + lrow) * 264 + bo];
            s8v bnh = *(const s8v*)&WbH[(32 + lrow) * 264 + bo];
            s8v bnl = *(const s8v*)&WbL[(32 + lrow) * 264 + bo];
            acc_r  = mfma16(ahi, brh, acc_r);
            acc_r  = mfma16(ahi, brl, acc_r);
            acc_r  = mfma16(alo, brh, acc_r);
            acc_z  = mfma16(ahi, bzh, acc_z);
            acc_z  = mfma16(ahi, bzl, acc_z);
            acc_z  = mfma16(alo, bzh, acc_z);
            acc_hn = mfma16(ahi, bnh, acc_hn);
            acc_hn = mfma16(ahi, bnl, acc_hn);
            acc_hn = mfma16(alo, bnh, acc_hn);
        }
        __syncthreads();
        if (c < 3) {
            #pragma unroll
            for (int i = 0; i < 6; ++i) {
                int c16 = i * 256 + tid;
                int row = c16 >> 5, p16 = c16 & 31;
                *(i4v*)&WbH[row * 264 + p16 * 8] = stgH[i];
                *(i4v*)&WbL[row * 264 + p16 * 8] = stgL[i];
            }
            __syncthreads();
        }
    }

    const int jcol = j0 + lrow;
    const float bhr = bhh[jcol];
    const float bhz = bhh[1024 + jcol];
    const float bhn = bhh[2048 + jcol];
    #pragma unroll
    for (int reg = 0; reg < 4; ++reg) {
        int brow = m0 + wave * 16 + lk8 * 4 + reg;
        gh_out[(size_t)brow * 3072 + jcol]        = acc_r[reg] + bhr;
        gh_out[(size_t)brow * 3072 + 1024 + jcol] = acc_z[reg] + bhz;
        gh_out[(size_t)brow * 3072 + 2048 + jcol] = acc_hn[reg] + bhn;
    }
}

// ---------------------------------------------------------------------------
// Fused decoder (unchanged from passing round)
__global__ __launch_bounds__(256, 1) void dec_fused(
    const u16* __restrict__ WihH, const u16* __restrict__ WihL,
    const float* __restrict__ bih,
    const float* __restrict__ xdec,
    const u16* __restrict__ ehi, const u16* __restrict__ elo,
    const float* __restrict__ gh,
    const u16* __restrict__ pWH, const u16* __restrict__ pWL,
    const float* __restrict__ pb,
    float* __restrict__ out)
{
    __shared__ u16 XdH[64 * 72];
    __shared__ u16 XdL[64 * 72];
    __shared__ u16 WiH_[192 * 72];
    __shared__ u16 WiL_[192 * 72];
    __shared__ u16 nsH[64 * 72];
    __shared__ u16 nsL[64 * 72];

    const int tid  = threadIdx.x;
    const int lane = tid & 63;
    const int wave = tid >> 6;
    const int lrow = lane & 15;
    const int lk8  = lane >> 4;
    const int b    = blockIdx.x;

    {
        int row = tid >> 2, q = tid & 3;
        const float* xr = xdec + (size_t)(b * 64 + row) * 63;
        #pragma unroll
        for (int ii = 0; ii < 16; ++ii) {
            int col = q * 16 + ii;
            float v = (col < 63) ? xr[col] : 0.f;
            u16 hh = f2b(v);
            XdH[row * 72 + col] = hh;
            XdL[row * 72 + col] = f2b(v - b2f(hh));
        }
    }

    f4v oacc[4];
    #pragma unroll
    for (int f = 0; f < 4; ++f) oacc[f] = f4v{0.f, 0.f, 0.f, 0.f};

    for (int j0 = 0; j0 < 1024; j0 += 64) {
        #pragma unroll
        for (int k = 0; k < 3; ++k) {
            int c = tid + k * 256;
            int r = c >> 2, qq = c & 3;
            int grow = (r >> 6) * 1024 + j0 + (r & 63);
            const u16* srcH = WihH + (size_t)grow * 64 + qq * 16;
            const u16* srcL = WihL + (size_t)grow * 64 + qq * 16;
            *(i4v*)&WiH_[r * 72 + qq * 16]     = *(const i4v*)srcH;
            *(i4v*)&WiH_[r * 72 + qq * 16 + 8] = *(const i4v*)(srcH + 8);
            *(i4v*)&WiL_[r * 72 + qq * 16]     = *(const i4v*)srcL;
            *(i4v*)&WiL_[r * 72 + qq * 16 + 8] = *(const i4v*)(srcL + 8);
        }
        __syncthreads();

        f4v ar[4], az[4], an[4];
        #pragma unroll
        for (int jf = 0; jf < 4; ++jf) {
            ar[jf] = f4v{0.f, 0.f, 0.f, 0.f};
            az[jf] = f4v{0.f, 0.f, 0.f, 0.f};
            an[jf] = f4v{0.f, 0.f, 0.f, 0.f};
        }
        #pragma unroll
        for (int ks = 0; ks < 2; ++ks) {
            int ao = ks * 32 + lk8 * 8;
            s8v ah = *(const s8v*)&XdH[(wave * 16 + lrow) * 72 + ao];
            s8v al = *(const s8v*)&XdL[(wave * 16 + lrow) * 72 + ao];
            #pragma unroll
            for (int jf = 0; jf < 4; ++jf) {
                s8v brh = *(const s8v*)&WiH_[(jf * 16 + lrow) * 72 + ao];
                s8v brl = *(const s8v*)&WiL_[(jf * 16 + lrow) * 72 + ao];
                s8v bzh = *(const s8v*)&WiH_[(64 + jf * 16 + lrow) * 72 + ao];
                s8v bzl = *(const s8v*)&WiL_[(64 + jf * 16 + lrow) * 72 + ao];
                s8v bnh = *(const s8v*)&WiH_[(128 + jf * 16 + lrow) * 72 + ao];
                s8v bnl = *(const s8v*)&WiL_[(128 + jf * 16 + lrow) * 72 + ao];
                ar[jf] = mfma16(ah, brh, ar[jf]);
                ar[jf] = mfma16(ah, brl, ar[jf]);
                ar[jf] = mfma16(al, brh, ar[jf]);
                az[jf] = mfma16(ah, bzh, az[jf]);
                az[jf] = mfma16(ah, bzl, az[jf]);
                az[jf] = mfma16(al, bzh, az[jf]);
                an[jf] = mfma16(ah, bnh, an[jf]);
                an[jf] = mfma16(ah, bnl, an[jf]);
                an[jf] = mfma16(al, bnh, an[jf]);
            }
        }

        #pragma unroll
        for (int jf = 0; jf < 4; ++jf) {
            int j = j0 + jf * 16 + lrow;
            float ghr = gh[(size_t)b * 3072 + j];
            float ghz = gh[(size_t)b * 3072 + 1024 + j];
            float ghn = gh[(size_t)b * 3072 + 2048 + j];
            float bir = bih[j];
            float biz = bih[1024 + j];
            float bin = bih[2048 + j];
            size_t eo = (size_t)b * 1024 + j;
            float he = b2f(ehi[eo]) + b2f(elo[eo]);
            #pragma unroll
            for (int reg = 0; reg < 4; ++reg) {
                float r  = sigf(ar[jf][reg] + bir + ghr);
                float z  = sigf(az[jf][reg] + biz + ghz);
                float nn = tanhf(an[jf][reg] + bin + r * ghn);
                float v  = (1.f - z) * nn + z * he;
                u16 hh = f2b(v);
                int lo_i = (wave * 16 + lk8 * 4 + reg) * 72 + jf * 16 + lrow;
                nsH[lo_i] = hh;
                nsL[lo_i] = f2b(v - b2f(hh));
            }
        }
        __syncthreads();

        #pragma unroll
        for (int ks = 0; ks < 2; ++ks) {
            int ao = ks * 32 + lk8 * 8;
            s8v ah = *(const s8v*)&nsH[(wave * 16 + lrow) * 72 + ao];
            s8v al = *(const s8v*)&nsL[(wave * 16 + lrow) * 72 + ao];
            #pragma unroll
            for (int f = 0; f < 4; ++f) {
                size_t bo = (size_t)(f * 16 + lrow) * 1024 + j0 + ks * 32 + lk8 * 8;
                s8v bh = *(const s8v*)(pWH + bo);
                s8v bl = *(const s8v*)(pWL + bo);
                oacc[f] = mfma16(ah, bh, oacc[f]);
                oacc[f] = mfma16(ah, bl, oacc[f]);
                oacc[f] = mfma16(al, bh, oacc[f]);
            }
        }
        __syncthreads();
    }

    #pragma unroll
    for (int f = 0; f < 4; ++f) {
        int o = f * 16 + lrow;
        if (o < 63) {
            float pbv = pb[o];
            #pragma unroll
            for (int reg = 0; reg < 4; ++reg) {
                int t = wave * 16 + lk8 * 4 + reg;
                out[((size_t)(b * 64 + t)) * 63 + o] = oacc[f][reg] + pbv;
            }
        }
    }
}

// ---------------------------------------------------------------------------
extern "C" void kernel_launch(void* const* d_in, const int* in_sizes, int n_in,
                              void* d_out, int out_size, void* d_ws, size_t ws_size,
                              hipStream_t stream)
{
    const float* enc_x = (const float*)d_in[0];
    const float* dec_x = (const float*)d_in[1];
    const float* eWih  = (const float*)d_in[2];
    const float* eWhh  = (const float*)d_in[3];
    const float* ebih  = (const float*)d_in[4];
    const float* ebhh  = (const float*)d_in[5];
    const float* dWih  = (const float*)d_in[6];
    const float* dWhh  = (const float*)d_in[7];
    const float* dbih  = (const float*)d_in[8];
    const float* dbhh  = (const float*)d_in[9];
    const float* pW    = (const float*)d_in[10];
    const float* pb    = (const float*)d_in[11];

    char* ws = (char*)d_ws;

    // ROT layout needs: 129MB hbuf + 16KB ep + 3MB ghd + 24MB Whh + 1.5MB Wih
    //                   + 256KB pW = 165429248 B
    const size_t ROT_NEED = 165429248ull;
    const bool rot = (ws_size >= ROT_NEED);

    u16 *hbuf, *Hfin_hi, *Hfin_lo;
    int* ep;
    float* ghd;
    u16 *eWhhH, *eWhhL, *dWhhH, *dWhhL;
    u16 *eWihH, *eWihL, *dWihH, *dWihL;
    u16 *pWH, *pWL;

    if (rot) {
        hbuf  = (u16*)(ws);                        // 129 x 1MB rotating h
        ep    = (int*)(ws + 135266304);            // 16 KB (group counters)
        ghd   = (float*)(ws + 135282688);          // 3 MB
        eWhhH = (u16*)(ws + 138428416);            // 6 MB each
        eWhhL = (u16*)(ws + 144719872);
        dWhhH = (u16*)(ws + 151011328);
        dWhhL = (u16*)(ws + 157302784);
        eWihH = (u16*)(ws + 163594240);            // 384 KB each
        eWihL = (u16*)(ws + 163987456);
        dWihH = (u16*)(ws + 164380672);
        dWihL = (u16*)(ws + 164773888);
        pWH   = (u16*)(ws + 165167104);            // 128 KB each
        pWL   = (u16*)(ws + 165298176);
        Hfin_hi = hbuf + (size_t)128 * 524288;     // buf[128] hi
        Hfin_lo = Hfin_hi + 262144;                // buf[128] lo
    } else {
        hbuf  = (u16*)(ws);                        // H0hi/H0lo/H1hi/H1lo (2 MB)
        ep    = (int*)(ws + 2097152);              // 256 epoch slots x 64 B
        ghd   = (float*)(ws + 3145728);            // 3 MB
        eWhhH = (u16*)(ws + 6291456);              // 6 MB each
        eWhhL = (u16*)(ws + 12582912);
        dWhhH = (u16*)(ws + 18874368);
        dWhhL = (u16*)(ws + 25165824);
        eWihH = (u16*)(ws + 31457280);             // 384 KB each (3072 x 64)
        eWihL = (u16*)(ws + 31850496);
        dWihH = (u16*)(ws + 32243712);
        dWihL = (u16*)(ws + 32636928);
        pWH   = (u16*)(ws + 33030144);             // 128 KB each (64 x 1024)
        pWL   = (u16*)(ws + 33161216);
        Hfin_hi = hbuf;                            // final enc_h in H0
        Hfin_lo = hbuf + 262144;
    }

    // one-time fp32 -> bf16 hi+lo weight conversions
    conv_split<<<dim3(4096), dim3(256), 0, stream>>>(eWhh, eWhhH, eWhhL, 3145728);
    conv_split<<<dim3(4096), dim3(256), 0, stream>>>(dWhh, dWhhH, dWhhL, 3145728);
    conv_wih_split_pad<<<dim3(768), dim3(256), 0, stream>>>(eWih, eWihH, eWihL);
    conv_wih_split_pad<<<dim3(768), dim3(256), 0, stream>>>(dWih, dWihH, dWihL);
    conv_pw_split_pad<<<dim3(256), dim3(256), 0, stream>>>(pW, pWH, pWL);

    if (rot) {
        // zero buf[0] (1 MB) + group counters (16 KB)
        zero_ws<<<dim3(256), dim3(256), 0, stream>>>((i4v*)hbuf, 65536);
        zero_ws<<<dim3(4), dim3(256), 0, stream>>>((i4v*)ep, 1024);
        enc_persist<1><<<dim3(256), dim3(512), 0, stream>>>(
            eWhhH, eWhhL, eWihH, eWihL, ebih, ebhh, enc_x, hbuf, ep);
    } else {
        // zero h buffers (2 MB) + epoch slots (16 KB)
        zero_ws<<<dim3(517), dim3(256), 0, stream>>>((i4v*)ws, 132096);
        enc_persist<0><<<dim3(256), dim3(512), 0, stream>>>(
            eWhhH, eWhhL, eWihH, eWihL, ebih, ebhh, enc_x, hbuf, ep);
    }

    // gh_dec = enc_h @ dec_Whh^T + dec_bhh
    gru_gemm1<<<dim3(256), dim3(256), 0, stream>>>(
        dWhhH, dWhhL, dbhh, Hfin_hi, Hfin_lo, ghd);

    // fused decoder gates + projection -> fp32 out
    dec_fused<<<dim3(256), dim3(256), 0, stream>>>(
        dWihH, dWihL, dbih, dec_x, Hfin_hi, Hfin_lo, ghd, pWH, pWL, pb,
        (float*)d_out);
}

// Round 2
// 1553.595 us; speedup vs baseline: 1.7606x; 1.0707x over previous
//
#include <hip/hip_runtime.h>

// Seq2Seq GRU: B=256, S=128, T=64, I=63, H=1024. Inputs fp32, output fp32.
// All GEMMs: bf16 hi+lo 3-term split emulation (~fp32 accuracy).
// Encoder v7: persistent kernel, 128 steps, fence-free rotating-buffer
//   protocol (round-1-proven). NEW this round:
//   - Whh (hi AND lo) is REGISTER-RESIDENT: each of 8 waves owns a disjoint
//     K-slice of 128 (24.5 KB = 96 VGPRs), loaded once. K-loop has zero LDS
//     traffic and zero syncthreads (was 96 ds_read_b128/wave/step + 1.07e8
//     bank-conflict cycles). Partials reduced 8-way via LDS (conflict-free
//     contiguous f4v pattern), 3 syncthreads/step total.
//   - Barrier counter split per-XCD: 8 sub-counters/mt-group (8 RMWs per
//     line instead of 64 serialized on one); poll checks 8 lines via lanes.
//     Same skew<=1 induction: sum>=8(s+1) per sub-ctr => all posted s+1.

typedef unsigned short u16;
typedef unsigned int   u32;
typedef __attribute__((ext_vector_type(8))) short s8v;   // 8 x bf16 (4 VGPRs)
typedef __attribute__((ext_vector_type(4))) float f4v;   // MFMA acc
typedef __attribute__((ext_vector_type(4))) int  i4v;    // 16B copy unit

__device__ __forceinline__ float b2f(u16 u) {
    return __uint_as_float(((u32)u) << 16);
}
__device__ __forceinline__ u16 f2b(float f) {   // round-to-nearest-even
    u32 x = __float_as_uint(f);
    u32 r = x + 0x7fffu + ((x >> 16) & 1u);
    return (u16)(r >> 16);
}
__device__ __forceinline__ float sigf(float x) {
    return 1.0f / (1.0f + __expf(-x));
}
__device__ __forceinline__ f4v mfma16(s8v a, s8v b, f4v c) {
    return __builtin_amdgcn_mfma_f32_16x16x32_bf16(a, b, c, 0, 0, 0);
}

// ---------------------------------------------------------------------------
__global__ void zero_ws(i4v* __restrict__ p, int n) {
    int i = blockIdx.x * blockDim.x + threadIdx.x;
    if (i < n) { i4v z = {0, 0, 0, 0}; p[i] = z; }
}

__global__ void conv_split(const float* __restrict__ s, u16* __restrict__ hi,
                           u16* __restrict__ lo, int n) {
    int i = blockIdx.x * blockDim.x + threadIdx.x;
    int st = gridDim.x * blockDim.x;
    for (; i < n; i += st) {
        float v = s[i];
        u16 h = f2b(v);
        hi[i] = h;
        lo[i] = f2b(v - b2f(h));
    }
}

// Wih (3072 x 63 fp32) -> padded (3072 x 64) hi+lo, col 63 = 0
__global__ void conv_wih_split_pad(const float* __restrict__ s,
                                   u16* __restrict__ hi, u16* __restrict__ lo) {
    int idx = blockIdx.x * blockDim.x + threadIdx.x;
    int row = idx >> 6, col = idx & 63;
    float v = (col < 63) ? s[(size_t)row * 63 + col] : 0.f;
    u16 h = f2b(v);
    hi[idx] = h;
    lo[idx] = f2b(v - b2f(h));
}

// proj_W (63 x 1024 fp32) -> padded (64 x 1024) hi+lo, row 63 = 0
__global__ void conv_pw_split_pad(const float* __restrict__ s,
                                  u16* __restrict__ hi, u16* __restrict__ lo) {
    int idx = blockIdx.x * blockDim.x + threadIdx.x;
    float v = (idx < 63 * 1024) ? s[idx] : 0.f;
    u16 h = f2b(v);
    hi[idx] = h;
    lo[idx] = f2b(v - b2f(h));
}

// ---------------------------------------------------------------------------
// Persistent encoder v7: register-resident Whh, per-XCD sub-counters.
__global__ __launch_bounds__(512, 1) void enc_persist_reg(
    const u16* __restrict__ WhhH, const u16* __restrict__ WhhL,
    const u16* __restrict__ WihH, const u16* __restrict__ WihL,
    const float* __restrict__ bih, const float* __restrict__ bhh,
    const float* __restrict__ xenc,
    u16* __restrict__ hbuf, int* __restrict__ ep)
{
    __shared__ f4v red[8][4][3][64];   // 98.3 KB: per-wave k-slice partials
    __shared__ u16 WisH[48 * 72];      // 6.75 KB each: Wih slice (persistent)
    __shared__ u16 WisL[48 * 72];

    // one-time: drop any stale lines from a previous graph replay
    __builtin_amdgcn_fence(__ATOMIC_ACQUIRE, "agent");

    const int tid  = threadIdx.x;
    const int lane = tid & 63;
    const int wave = tid >> 6;          // 0..7 : k-slice owner, k0 = wave*128
    const int lrow = lane & 15;
    const int lk8  = lane >> 4;
    // XCD-aware swizzle: bid&7 = XCD; XCD owns a 128-col j-range.
    const int bid = blockIdx.x;
    const int xcd = bid & 7;
    const int y   = bid >> 3;
    const int mt  = y & 3;
    const int jt  = xcd * 8 + (y >> 2);
    const int m0 = mt * 64;
    const int j0 = jt * 16;

    // per-(mt,XCD) sub-counter; 8 blocks post each; 64B line spacing
    int* subCtr  = ep + (mt * 8 + xcd) * 16;
    int* pollCtr = ep + (mt * 8 + (lane & 7)) * 16;

    // ---- one-time: Wih slice into LDS
    if (tid < 192) {
        int wr = tid >> 2, qq = tid & 3;
        int grow = (wr >> 4) * 1024 + j0 + (wr & 15);
        const u16* wpH = WihH + (size_t)grow * 64 + qq * 16;
        const u16* wpL = WihL + (size_t)grow * 64 + qq * 16;
        *(i4v*)&WisH[wr * 72 + qq * 16]     = *(const i4v*)wpH;
        *(i4v*)&WisH[wr * 72 + qq * 16 + 8] = *(const i4v*)(wpH + 8);
        *(i4v*)&WisL[wr * 72 + qq * 16]     = *(const i4v*)wpL;
        *(i4v*)&WisL[wr * 72 + qq * 16 + 8] = *(const i4v*)(wpL + 8);
    }

    // ---- one-time: this wave's Whh K-slice into registers (hi+lo, 96 VGPR)
    s8v bHf[3][4], bLf[3][4];
    const int k0 = wave * 128;
    #pragma unroll
    for (int gg = 0; gg < 3; ++gg)
        #pragma unroll
        for (int ks = 0; ks < 4; ++ks) {
            size_t off = (size_t)(gg * 1024 + j0 + lrow) * 1024 +
                         k0 + ks * 32 + lk8 * 8;
            bHf[gg][ks] = *(const s8v*)(WhhH + off);
            bLf[gg][ks] = *(const s8v*)(WhhL + off);
        }

    const int jcol = j0 + lrow;
    const float bhr = bhh[jcol], bhz = bhh[1024 + jcol], bhn = bhh[2048 + jcol];
    const float bir = bih[jcol], biz = bih[1024 + jcol], bin = bih[2048 + jcol];

    // A-load offsets per m-tile (lane's 16B segment within its K-slice)
    size_t aoff[4];
    #pragma unroll
    for (int mtile = 0; mtile < 4; ++mtile)
        aoff[mtile] = (size_t)(m0 + mtile * 16 + lrow) * 1024 + k0 + lk8 * 8;

    // gi / epilogue waves: wave v (0..3) owns m-tile v
    const float* xrow = xenc + (size_t)(m0 + (wave & 3) * 16 + lrow) * 8064;
    float hprev[4] = {0.f, 0.f, 0.f, 0.f};

    float xf[16];
    if (wave < 4) {
        #pragma unroll
        for (int ks = 0; ks < 2; ++ks)
            #pragma unroll
            for (int j = 0; j < 8; ++j) {
                int col = ks * 32 + lk8 * 8 + j;
                xf[ks * 8 + j] = (col < 63) ? xrow[col] : 0.f;
            }
    }

    __syncthreads();   // Wis ready

    for (int s = 0; s < 128; ++s) {
        // rotating: read buf[s], write buf[s+1]; each 1MB = hi(256K u16)+lo
        const u16* hinH = hbuf + (size_t)s * 524288;
        const u16* hinL = hinH + 262144;
        u16* houtH = hbuf + (size_t)(s + 1) * 524288;
        u16* houtL = houtH + 262144;

        f4v accr[4], accz[4], acchn[4];
        #pragma unroll
        for (int m = 0; m < 4; ++m) {
            accr[m]  = f4v{0.f, 0.f, 0.f, 0.f};
            accz[m]  = f4v{0.f, 0.f, 0.f, 0.f};
            acchn[m] = f4v{0.f, 0.f, 0.f, 0.f};
        }
        f4v gi_r = {0.f, 0.f, 0.f, 0.f};
        f4v gi_z = {0.f, 0.f, 0.f, 0.f};
        f4v gi_n = {0.f, 0.f, 0.f, 0.f};

        // ---- gi (waves 0-3, m-tile = wave): x @ Wih^T, K=64 padded
        if (wave < 4) {
            #pragma unroll
            for (int ks = 0; ks < 2; ++ks) {
                union { u16 a[8]; s8v v; } xh, xl;
                #pragma unroll
                for (int j = 0; j < 8; ++j) {
                    float v = xf[ks * 8 + j];
                    u16 hh = f2b(v);
                    xh.a[j] = hh;
                    xl.a[j] = f2b(v - b2f(hh));
                }
                int ao = ks * 32 + lk8 * 8;
                s8v brh = *(const s8v*)&WisH[(lrow) * 72 + ao];
                s8v brl = *(const s8v*)&WisL[(lrow) * 72 + ao];
                s8v bzh = *(const s8v*)&WisH[(16 + lrow) * 72 + ao];
                s8v bzl = *(const s8v*)&WisL[(16 + lrow) * 72 + ao];
                s8v bnh = *(const s8v*)&WisH[(32 + lrow) * 72 + ao];
                s8v bnl = *(const s8v*)&WisL[(32 + lrow) * 72 + ao];
                gi_r = mfma16(xh.v, brh, gi_r);
                gi_r = mfma16(xh.v, brl, gi_r);
                gi_r = mfma16(xl.v, brh, gi_r);
                gi_z = mfma16(xh.v, bzh, gi_z);
                gi_z = mfma16(xh.v, bzl, gi_z);
                gi_z = mfma16(xl.v, bzh, gi_z);
                gi_n = mfma16(xh.v, bnh, gi_n);
                gi_n = mfma16(xh.v, bnl, gi_n);
                gi_n = mfma16(xl.v, bnh, gi_n);
            }
        }

        // ---- K loop: 4 m-tiles x 4 ks, B from registers, NO LDS, NO sync
        #pragma unroll
        for (int mtile = 0; mtile < 4; ++mtile) {
            #pragma unroll
            for (int ks = 0; ks < 4; ++ks) {
                s8v ahi = *(const s8v*)(hinH + aoff[mtile] + ks * 32);
                s8v alo = *(const s8v*)(hinL + aoff[mtile] + ks * 32);
                accr[mtile]  = mfma16(ahi, bHf[0][ks], accr[mtile]);
                accr[mtile]  = mfma16(ahi, bLf[0][ks], accr[mtile]);
                accr[mtile]  = mfma16(alo, bHf[0][ks], accr[mtile]);
                accz[mtile]  = mfma16(ahi, bHf[1][ks], accz[mtile]);
                accz[mtile]  = mfma16(ahi, bLf[1][ks], accz[mtile]);
                accz[mtile]  = mfma16(alo, bHf[1][ks], accz[mtile]);
                acchn[mtile] = mfma16(ahi, bHf[2][ks], acchn[mtile]);
                acchn[mtile] = mfma16(ahi, bLf[2][ks], acchn[mtile]);
                acchn[mtile] = mfma16(alo, bHf[2][ks], acchn[mtile]);
            }
        }

        // ---- write k-slice partials (fold gi into wave's own m-tile)
        #pragma unroll
        for (int m = 0; m < 4; ++m) {
            f4v pr = accr[m], pz = accz[m];
            if (wave == m) { pr += gi_r; pz += gi_z; }   // waves 0-3 only
            red[wave][m][0][lane] = pr;
            red[wave][m][1][lane] = pz;
            red[wave][m][2][lane] = acchn[m];
        }
        __syncthreads();

        // ---- epilogue (waves 0-3): 8-way reduce, gates, h store
        if (wave < 4) {
            f4v sr = {0.f, 0.f, 0.f, 0.f};
            f4v sz = {0.f, 0.f, 0.f, 0.f};
            f4v sh = {0.f, 0.f, 0.f, 0.f};
            #pragma unroll
            for (int w = 0; w < 8; ++w) {
                sr += red[w][wave][0][lane];
                sz += red[w][wave][1][lane];
                sh += red[w][wave][2][lane];
            }
            #pragma unroll
            for (int reg = 0; reg < 4; ++reg) {
                int brow = m0 + wave * 16 + lk8 * 4 + reg;
                float rr = sigf(sr[reg] + bir + bhr);
                float zz = sigf(sz[reg] + biz + bhz);
                float nn = tanhf(gi_n[reg] + bin + rr * (sh[reg] + bhn));
                float h = (1.f - zz) * nn + zz * hprev[reg];
                u16 hh = f2b(h);
                u16 ll = f2b(h - b2f(hh));
                hprev[reg] = b2f(hh) + b2f(ll);
                size_t off = (size_t)brow * 1024 + jcol;
                // write-through (sc0 sc1): visible once vmcnt drains at the
                // barrier below -> no wbl2 needed.
                __hip_atomic_store(&houtH[off], hh, __ATOMIC_RELAXED,
                                   __HIP_MEMORY_SCOPE_SYSTEM);
                __hip_atomic_store(&houtL[off], ll, __ATOMIC_RELAXED,
                                   __HIP_MEMORY_SCOPE_SYSTEM);
            }
        }

        __syncthreads();   // drains h stores (vmcnt 0 per wave)
        if (tid == 0)
            __hip_atomic_fetch_add(subCtr, 1, __ATOMIC_RELAXED,
                                   __HIP_MEMORY_SCOPE_SYSTEM);
        // prefetch next step's x behind the poll (immutable input)
        if (wave < 4) {
            int sn = (s < 127) ? s + 1 : 127;
            const float* xr = xrow + sn * 63;
            #pragma unroll
            for (int ks = 0; ks < 2; ++ks)
                #pragma unroll
                for (int j = 0; j < 8; ++j) {
                    int col = ks * 32 + lk8 * 8 + j;
                    xf[ks * 8 + j] = (col < 63) ? xr[col] : 0.f;
                }
        }
        if (wave == 0) {
            // lanes check 8 sub-counters (lane&7); sum>=8(s+1) per sub-ctr
            // <=> all 8 of its blocks posted s+1 (skew<=1 induction).
            int tgt = (s + 1) * 8;
            for (;;) {
                int v = __hip_atomic_load(pollCtr, __ATOMIC_RELAXED,
                                          __HIP_MEMORY_SCOPE_SYSTEM);
                if (__all(v >= tgt)) break;
                __builtin_amdgcn_s_sleep(1);
            }
        }
        __syncthreads();
    }
}

// ---------------------------------------------------------------------------
// Legacy fallback encoder (round-8-proven fence+slot protocol). Only used
// when ws_size is too small for the rotating layout. Unchanged semantics.
__global__ __launch_bounds__(512, 1) void enc_persist_legacy(
    const u16* __restrict__ WhhH, const u16* __restrict__ WhhL,
    const u16* __restrict__ WihH, const u16* __restrict__ WihL,
    const float* __restrict__ bih, const float* __restrict__ bhh,
    const float* __restrict__ xenc,
    u16* __restrict__ hbuf, int* __restrict__ ep)
{
    __shared__ u16 BH[48 * 1032];
    __shared__ u16 BLs[2][48 * 136];
    __shared__ u16 WisH[48 * 72];
    __shared__ u16 WisL[48 * 72];
    __shared__ f4v red[4][3][64];

    const int tid  = threadIdx.x;
    const int lane = tid & 63;
    const int wave = tid >> 6;
    const int g    = wave >> 2;
    const int wv   = wave & 3;
    const int gtid = tid & 255;
    const int lrow = lane & 15;
    const int lk8  = lane >> 4;
    const int bid = blockIdx.x;
    const int y   = bid >> 3;
    const int mt  = y & 3;
    const int jt  = (bid & 7) * 8 + (y >> 2);
    const int m0 = mt * 64;
    const int j0 = jt * 16;

    int* mySlot   = ep + (mt * 64 + jt) * 16;
    int* laneSlot = ep + (mt * 64 + lane) * 16;

    #pragma unroll
    for (int i = 0; i < 12; ++i) {
        int u = i * 512 + tid;
        int row = u >> 7, p = u & 127;
        int grow = (row >> 4) * 1024 + j0 + (row & 15);
        *(i4v*)&BH[row * 1032 + p * 8] = *(const i4v*)(WhhH + (size_t)grow * 1024 + p * 8);
    }
    if (tid < 192) {
        int wr = tid >> 2, qq = tid & 3;
        int grow = (wr >> 4) * 1024 + j0 + (wr & 15);
        const u16* wpH = WihH + (size_t)grow * 64 + qq * 16;
        const u16* wpL = WihL + (size_t)grow * 64 + qq * 16;
        *(i4v*)&WisH[wr * 72 + qq * 16]     = *(const i4v*)wpH;
        *(i4v*)&WisH[wr * 72 + qq * 16 + 8] = *(const i4v*)(wpH + 8);
        *(i4v*)&WisL[wr * 72 + qq * 16]     = *(const i4v*)wpL;
        *(i4v*)&WisL[wr * 72 + qq * 16 + 8] = *(const i4v*)(wpL + 8);
    }

    const int jcol = j0 + lrow;
    const float bhr = bhh[jcol], bhz = bhh[1024 + jcol], bhn = bhh[2048 + jcol];
    const float bir = bih[jcol], biz = bih[1024 + jcol], bin = bih[2048 + jcol];

    int blrow[3], blp[3], blgrow[3];
    #pragma unroll
    for (int i = 0; i < 3; ++i) {
        int u = i * 256 + gtid;
        blrow[i] = u >> 4;
        blp[i]   = u & 15;
        blgrow[i] = (blrow[i] >> 4) * 1024 + j0 + (blrow[i] & 15);
    }

    const size_t arow = (size_t)(m0 + wv * 16 + lrow) * 1024 + lk8 * 8;
    const int kbase = g * 512;
    const float* xrow = xenc + (size_t)(m0 + wv * 16 + lrow) * 8064;

    float hprev[4] = {0.f, 0.f, 0.f, 0.f};

    i4v stgL[3];
    #pragma unroll
    for (int i = 0; i < 3; ++i)
        stgL[i] = *(const i4v*)(WhhL + (size_t)blgrow[i] * 1024 + kbase + blp[i] * 8);
    float xf[16];
    if (g == 0) {
        #pragma unroll
        for (int ks = 0; ks < 2; ++ks)
            #pragma unroll
            for (int j = 0; j < 8; ++j) {
                int col = ks * 32 + lk8 * 8 + j;
                xf[ks * 8 + j] = (col < 63) ? xrow[col] : 0.f;
            }
    }

    __syncthreads();

    for (int s = 0; s < 128; ++s) {
        const u16 *hinH, *hinL; u16 *houtH, *houtL;
        if (s & 1) {
            hinH = hbuf + 524288; hinL = hbuf + 786432;
            houtH = hbuf;         houtL = hbuf + 262144;
        } else {
            hinH = hbuf;          hinL = hbuf + 262144;
            houtH = hbuf + 524288; houtL = hbuf + 786432;
        }

        #pragma unroll
        for (int i = 0; i < 3; ++i)
            *(i4v*)&BLs[g][blrow[i] * 136 + blp[i] * 8] = stgL[i];
        __syncthreads();

        f4v acc_r  = {0.f, 0.f, 0.f, 0.f};
        f4v acc_z  = {0.f, 0.f, 0.f, 0.f};
        f4v acc_gn = {0.f, 0.f, 0.f, 0.f};
        f4v acc_hn = {0.f, 0.f, 0.f, 0.f};

        if (g == 0) {
            #pragma unroll
            for (int ks = 0; ks < 2; ++ks) {
                union { u16 a[8]; s8v v; } xh, xl;
                #pragma unroll
                for (int j = 0; j < 8; ++j) {
                    float v = xf[ks * 8 + j];
                    u16 hh = f2b(v);
                    xh.a[j] = hh;
                    xl.a[j] = f2b(v - b2f(hh));
                }
                int ao = ks * 32 + lk8 * 8;
                s8v brh = *(const s8v*)&WisH[(lrow) * 72 + ao];
                s8v brl = *(const s8v*)&WisL[(lrow) * 72 + ao];
                s8v bzh = *(const s8v*)&WisH[(16 + lrow) * 72 + ao];
                s8v bzl = *(const s8v*)&WisL[(16 + lrow) * 72 + ao];
                s8v bnh = *(const s8v*)&WisH[(32 + lrow) * 72 + ao];
                s8v bnl = *(const s8v*)&WisL[(32 + lrow) * 72 + ao];
                acc_r  = mfma16(xh.v, brh, acc_r);
                acc_r  = mfma16(xh.v, brl, acc_r);
                acc_r  = mfma16(xl.v, brh, acc_r);
                acc_z  = mfma16(xh.v, bzh, acc_z);
                acc_z  = mfma16(xh.v, bzl, acc_z);
                acc_z  = mfma16(xl.v, bzh, acc_z);
                acc_gn = mfma16(xh.v, bnh, acc_gn);
                acc_gn = mfma16(xh.v, bnl, acc_gn);
                acc_gn = mfma16(xl.v, bnh, acc_gn);
            }
        }

        const u16* hp = hinH + arow;
        const u16* lp = hinL + arow;

        for (int c = 0; c < 4; ++c) {
            if (c < 3) {
                #pragma unroll
                for (int i = 0; i < 3; ++i)
                    stgL[i] = *(const i4v*)(WhhL + (size_t)blgrow[i] * 1024 +
                                            kbase + (c + 1) * 128 + blp[i] * 8);
            }
            #pragma unroll
            for (int ks = 0; ks < 4; ++ks) {
                int kk = kbase + c * 128 + ks * 32;
                int bh = kk + lk8 * 8;
                int bl = ks * 32 + lk8 * 8;
                s8v ahi = *(const s8v*)(hp + kk);
                s8v alo = *(const s8v*)(lp + kk);
                s8v brh = *(const s8v*)&BH[(lrow) * 1032 + bh];
                s8v brl = *(const s8v*)&BLs[g][(lrow) * 136 + bl];
                s8v bzh = *(const s8v*)&BH[(16 + lrow) * 1032 + bh];
                s8v bzl = *(const s8v*)&BLs[g][(16 + lrow) * 136 + bl];
                s8v bnh = *(const s8v*)&BH[(32 + lrow) * 1032 + bh];
                s8v bnl = *(const s8v*)&BLs[g][(32 + lrow) * 136 + bl];
                acc_r  = mfma16(ahi, brh, acc_r);
                acc_r  = mfma16(ahi, brl, acc_r);
                acc_r  = mfma16(alo, brh, acc_r);
                acc_z  = mfma16(ahi, bzh, acc_z);
                acc_z  = mfma16(ahi, bzl, acc_z);
                acc_z  = mfma16(alo, bzh, acc_z);
                acc_hn = mfma16(ahi, bnh, acc_hn);
                acc_hn = mfma16(ahi, bnl, acc_hn);
                acc_hn = mfma16(alo, bnh, acc_hn);
            }
            __syncthreads();
            if (c < 3) {
                #pragma unroll
                for (int i = 0; i < 3; ++i)
                    *(i4v*)&BLs[g][blrow[i] * 136 + blp[i] * 8] = stgL[i];
                __syncthreads();
            }
        }

        if (g == 1) {
            red[wv][0][lane] = acc_r;
            red[wv][1][lane] = acc_z;
            red[wv][2][lane] = acc_hn;
        }
        __syncthreads();
        if (g == 0) {
            f4v r1 = red[wv][0][lane];
            f4v z1 = red[wv][1][lane];
            f4v n1 = red[wv][2][lane];
            #pragma unroll
            for (int reg = 0; reg < 4; ++reg) {
                int brow = m0 + wv * 16 + lk8 * 4 + reg;
                float rr = sigf(acc_r[reg] + r1[reg] + bir + bhr);
                float zz = sigf(acc_z[reg] + z1[reg] + biz + bhz);
                float nn = tanhf(acc_gn[reg] + bin + rr * (acc_hn[reg] + n1[reg] + bhn));
                float h = (1.f - zz) * nn + zz * hprev[reg];
                u16 hh = f2b(h);
                u16 ll = f2b(h - b2f(hh));
                hprev[reg] = b2f(hh) + b2f(ll);
                size_t off = (size_t)brow * 1024 + jcol;
                houtH[off] = hh;
                houtL[off] = ll;
            }
        }

        __syncthreads();
        if (tid == 0) {
            __builtin_amdgcn_fence(__ATOMIC_RELEASE, "agent");
            __hip_atomic_store(mySlot, s + 1, __ATOMIC_RELAXED,
                               __HIP_MEMORY_SCOPE_AGENT);
        }
        #pragma unroll
        for (int i = 0; i < 3; ++i)
            stgL[i] = *(const i4v*)(WhhL + (size_t)blgrow[i] * 1024 + kbase + blp[i] * 8);
        if (g == 0) {
            int sn = (s < 127) ? s + 1 : 127;
            const float* xr = xrow + sn * 63;
            #pragma unroll
            for (int ks = 0; ks < 2; ++ks)
                #pragma unroll
                for (int j = 0; j < 8; ++j) {
                    int col = ks * 32 + lk8 * 8 + j;
                    xf[ks * 8 + j] = (col < 63) ? xr[col] : 0.f;
                }
        }
        if (wave == 0) {
            for (;;) {
                int v = __hip_atomic_load(laneSlot, __ATOMIC_RELAXED,
                                          __HIP_MEMORY_SCOPE_AGENT);
                if (__all(v >= s + 1)) break;
                __builtin_amdgcn_s_sleep(2);
            }
            __builtin_amdgcn_fence(__ATOMIC_ACQUIRE, "agent");
        }
        __syncthreads();
    }
}

// ---------------------------------------------------------------------------
// gh_dec = enc_h @ dec_Whh^T + dec_bhh (fp32 out).
__global__ __launch_bounds__(256, 1) void gru_gemm1(
    const u16* __restrict__ WhhH, const u16* __restrict__ WhhL,
    const float* __restrict__ bhh,
    const u16* __restrict__ hin_hi, const u16* __restrict__ hin_lo,
    float* __restrict__ gh_out)
{
    __shared__ u16 WbH[48 * 264];
    __shared__ u16 WbL[48 * 264];

    const int tid  = threadIdx.x;
    const int lane = tid & 63;
    const int wave = tid >> 6;
    const int lrow = lane & 15;
    const int lk8  = lane >> 4;
    const int mt = blockIdx.x & 3;
    const int jt = blockIdx.x >> 2;
    const int m0 = mt * 64;
    const int j0 = jt * 16;

    f4v acc_r  = {0.f, 0.f, 0.f, 0.f};
    f4v acc_z  = {0.f, 0.f, 0.f, 0.f};
    f4v acc_hn = {0.f, 0.f, 0.f, 0.f};

    i4v stgH[6], stgL[6];
    #pragma unroll
    for (int i = 0; i < 6; ++i) {
        int c16 = i * 256 + tid;
        int row = c16 >> 5, p16 = c16 & 31;
        int grow = (row >> 4) * 1024 + j0 + (row & 15);
        size_t off = (size_t)grow * 1024 + p16 * 8;
        stgH[i] = *(const i4v*)(WhhH + off);
        stgL[i] = *(const i4v*)(WhhL + off);
    }
    #pragma unroll
    for (int i = 0; i < 6; ++i) {
        int c16 = i * 256 + tid;
        int row = c16 >> 5, p16 = c16 & 31;
        *(i4v*)&WbH[row * 264 + p16 * 8] = stgH[i];
        *(i4v*)&WbL[row * 264 + p16 * 8] = stgL[i];
    }
    __syncthreads();

    const size_t arow = (size_t)(m0 + wave * 16 + lrow) * 1024 + lk8 * 8;
    const u16* hp = hin_hi + arow;
    const u16* lp = hin_lo + arow;

    for (int c = 0; c < 4; ++c) {
        if (c < 3) {
            #pragma unroll
            for (int i = 0; i < 6; ++i) {
                int c16 = i * 256 + tid;
                int row = c16 >> 5, p16 = c16 & 31;
                int grow = (row >> 4) * 1024 + j0 + (row & 15);
                size_t off = (size_t)grow * 1024 + (c + 1) * 256 + p16 * 8;
                stgH[i] = *(const i4v*)(WhhH + off);
                stgL[i] = *(const i4v*)(WhhL + off);
            }
        }
        #pragma unroll
        for (int ks = 0; ks < 8; ++ks) {
            int kk = c * 256 + ks * 32;
            int bo = ks * 32 + lk8 * 8;
            s8v ahi = *(const s8v*)(hp + kk);
            s8v alo = *(const s8v*)(lp + kk);
            s8v brh = *(const s8v*)&WbH[(lrow) * 264 + bo];
            s8v brl = *(const s8v*)&WbL[(lrow) * 264 + bo];
            s8v bzh = *(const s8v*)&WbH[(16 + lrow) * 264 + bo];
            s8v bzl = *(const s8v*)&WbL[(16 + lrow) * 264 + bo];
            s8v bnh = *(const s8v*)&WbH[(32 + lrow) * 264 + bo];
            s8v bnl = *(const s8v*)&WbL[(32 + lrow) * 264 + bo];
            acc_r  = mfma16(ahi, brh, acc_r);
            acc_r  = mfma16(ahi, brl, acc_r);
            acc_r  = mfma16(alo, brh, acc_r);
            acc_z  = mfma16(ahi, bzh, acc_z);
            acc_z  = mfma16(ahi, bzl, acc_z);
            acc_z  = mfma16(alo, bzh, acc_z);
            acc_hn = mfma16(ahi, bnh, acc_hn);
            acc_hn = mfma16(ahi, bnl, acc_hn);
            acc_hn = mfma16(alo, bnh, acc_hn);
        }
        __syncthreads();
        if (c < 3) {
            #pragma unroll
            for (int i = 0; i < 6; ++i) {
                int c16 = i * 256 + tid;
                int row = c16 >> 5, p16 = c16 & 31;
                *(i4v*)&WbH[row * 264 + p16 * 8] = stgH[i];
                *(i4v*)&WbL[row * 264 + p16 * 8] = stgL[i];
            }
            __syncthreads();
        }
    }

    const int jcol = j0 + lrow;
    const float bhr = bhh[jcol];
    const float bhz = bhh[1024 + jcol];
    const float bhn = bhh[2048 + jcol];
    #pragma unroll
    for (int reg = 0; reg < 4; ++reg) {
        int brow = m0 + wave * 16 + lk8 * 4 + reg;
        gh_out[(size_t)brow * 3072 + jcol]        = acc_r[reg] + bhr;
        gh_out[(size_t)brow * 3072 + 1024 + jcol] = acc_z[reg] + bhz;
        gh_out[(size_t)brow * 3072 + 2048 + jcol] = acc_hn[reg] + bhn;
    }
}

// ---------------------------------------------------------------------------
// Fused decoder (unchanged from passing round)
__global__ __launch_bounds__(256, 1) void dec_fused(
    const u16* __restrict__ WihH, const u16* __restrict__ WihL,
    const float* __restrict__ bih,
    const float* __restrict__ xdec,
    const u16* __restrict__ ehi, const u16* __restrict__ elo,
    const float* __restrict__ gh,
    const u16* __restrict__ pWH, const u16* __restrict__ pWL,
    const float* __restrict__ pb,
    float* __restrict__ out)
{
    __shared__ u16 XdH[64 * 72];
    __shared__ u16 XdL[64 * 72];
    __shared__ u16 WiH_[192 * 72];
    __shared__ u16 WiL_[192 * 72];
    __shared__ u16 nsH[64 * 72];
    __shared__ u16 nsL[64 * 72];

    const int tid  = threadIdx.x;
    const int lane = tid & 63;
    const int wave = tid >> 6;
    const int lrow = lane & 15;
    const int lk8  = lane >> 4;
    const int b    = blockIdx.x;

    {
        int row = tid >> 2, q = tid & 3;
        const float* xr = xdec + (size_t)(b * 64 + row) * 63;
        #pragma unroll
        for (int ii = 0; ii < 16; ++ii) {
            int col = q * 16 + ii;
            float v = (col < 63) ? xr[col] : 0.f;
            u16 hh = f2b(v);
            XdH[row * 72 + col] = hh;
            XdL[row * 72 + col] = f2b(v - b2f(hh));
        }
    }

    f4v oacc[4];
    #pragma unroll
    for (int f = 0; f < 4; ++f) oacc[f] = f4v{0.f, 0.f, 0.f, 0.f};

    for (int j0 = 0; j0 < 1024; j0 += 64) {
        #pragma unroll
        for (int k = 0; k < 3; ++k) {
            int c = tid + k * 256;
            int r = c >> 2, qq = c & 3;
            int grow = (r >> 6) * 1024 + j0 + (r & 63);
            const u16* srcH = WihH + (size_t)grow * 64 + qq * 16;
            const u16* srcL = WihL + (size_t)grow * 64 + qq * 16;
            *(i4v*)&WiH_[r * 72 + qq * 16]     = *(const i4v*)srcH;
            *(i4v*)&WiH_[r * 72 + qq * 16 + 8] = *(const i4v*)(srcH + 8);
            *(i4v*)&WiL_[r * 72 + qq * 16]     = *(const i4v*)srcL;
            *(i4v*)&WiL_[r * 72 + qq * 16 + 8] = *(const i4v*)(srcL + 8);
        }
        __syncthreads();

        f4v ar[4], az[4], an[4];
        #pragma unroll
        for (int jf = 0; jf < 4; ++jf) {
            ar[jf] = f4v{0.f, 0.f, 0.f, 0.f};
            az[jf] = f4v{0.f, 0.f, 0.f, 0.f};
            an[jf] = f4v{0.f, 0.f, 0.f, 0.f};
        }
        #pragma unroll
        for (int ks = 0; ks < 2; ++ks) {
            int ao = ks * 32 + lk8 * 8;
            s8v ah = *(const s8v*)&XdH[(wave * 16 + lrow) * 72 + ao];
            s8v al = *(const s8v*)&XdL[(wave * 16 + lrow) * 72 + ao];
            #pragma unroll
            for (int jf = 0; jf < 4; ++jf) {
                s8v brh = *(const s8v*)&WiH_[(jf * 16 + lrow) * 72 + ao];
                s8v brl = *(const s8v*)&WiL_[(jf * 16 + lrow) * 72 + ao];
                s8v bzh = *(const s8v*)&WiH_[(64 + jf * 16 + lrow) * 72 + ao];
                s8v bzl = *(const s8v*)&WiL_[(64 + jf * 16 + lrow) * 72 + ao];
                s8v bnh = *(const s8v*)&WiH_[(128 + jf * 16 + lrow) * 72 + ao];
                s8v bnl = *(const s8v*)&WiL_[(128 + jf * 16 + lrow) * 72 + ao];
                ar[jf] = mfma16(ah, brh, ar[jf]);
                ar[jf] = mfma16(ah, brl, ar[jf]);
                ar[jf] = mfma16(al, brh, ar[jf]);
                az[jf] = mfma16(ah, bzh, az[jf]);
                az[jf] = mfma16(ah, bzl, az[jf]);
                az[jf] = mfma16(al, bzh, az[jf]);
                an[jf] = mfma16(ah, bnh, an[jf]);
                an[jf] = mfma16(ah, bnl, an[jf]);
                an[jf] = mfma16(al, bnh, an[jf]);
            }
        }

        #pragma unroll
        for (int jf = 0; jf < 4; ++jf) {
            int j = j0 + jf * 16 + lrow;
            float ghr = gh[(size_t)b * 3072 + j];
            float ghz = gh[(size_t)b * 3072 + 1024 + j];
            float ghn = gh[(size_t)b * 3072 + 2048 + j];
            float bir = bih[j];
            float biz = bih[1024 + j];
            float bin = bih[2048 + j];
            size_t eo = (size_t)b * 1024 + j;
            float he = b2f(ehi[eo]) + b2f(elo[eo]);
            #pragma unroll
            for (int reg = 0; reg < 4; ++reg) {
                float r  = sigf(ar[jf][reg] + bir + ghr);
                float z  = sigf(az[jf][reg] + biz + ghz);
                float nn = tanhf(an[jf][reg] + bin + r * ghn);
                float v  = (1.f - z) * nn + z * he;
                u16 hh = f2b(v);
                int lo_i = (wave * 16 + lk8 * 4 + reg) * 72 + jf * 16 + lrow;
                nsH[lo_i] = hh;
                nsL[lo_i] = f2b(v - b2f(hh));
            }
        }
        __syncthreads();

        #pragma unroll
        for (int ks = 0; ks < 2; ++ks) {
            int ao = ks * 32 + lk8 * 8;
            s8v ah = *(const s8v*)&nsH[(wave * 16 + lrow) * 72 + ao];
            s8v al = *(const s8v*)&nsL[(wave * 16 + lrow) * 72 + ao];
            #pragma unroll
            for (int f = 0; f < 4; ++f) {
                size_t bo = (size_t)(f * 16 + lrow) * 1024 + j0 + ks * 32 + lk8 * 8;
                s8v bh = *(const s8v*)(pWH + bo);
                s8v bl = *(const s8v*)(pWL + bo);
                oacc[f] = mfma16(ah, bh, oacc[f]);
                oacc[f] = mfma16(ah, bl, oacc[f]);
                oacc[f] = mfma16(al, bh, oacc[f]);
            }
        }
        __syncthreads();
    }

    #pragma unroll
    for (int f = 0; f < 4; ++f) {
        int o = f * 16 + lrow;
        if (o < 63) {
            float pbv = pb[o];
            #pragma unroll
            for (int reg = 0; reg < 4; ++reg) {
                int t = wave * 16 + lk8 * 4 + reg;
                out[((size_t)(b * 64 + t)) * 63 + o] = oacc[f][reg] + pbv;
            }
        }
    }
}

// ---------------------------------------------------------------------------
extern "C" void kernel_launch(void* const* d_in, const int* in_sizes, int n_in,
                              void* d_out, int out_size, void* d_ws, size_t ws_size,
                              hipStream_t stream)
{
    const float* enc_x = (const float*)d_in[0];
    const float* dec_x = (const float*)d_in[1];
    const float* eWih  = (const float*)d_in[2];
    const float* eWhh  = (const float*)d_in[3];
    const float* ebih  = (const float*)d_in[4];
    const float* ebhh  = (const float*)d_in[5];
    const float* dWih  = (const float*)d_in[6];
    const float* dWhh  = (const float*)d_in[7];
    const float* dbih  = (const float*)d_in[8];
    const float* dbhh  = (const float*)d_in[9];
    const float* pW    = (const float*)d_in[10];
    const float* pb    = (const float*)d_in[11];

    char* ws = (char*)d_ws;

    // ROT layout needs: 129MB hbuf + 16KB ep + 3MB ghd + 24MB Whh + 1.5MB Wih
    //                   + 256KB pW = 165429248 B
    const size_t ROT_NEED = 165429248ull;
    const bool rot = (ws_size >= ROT_NEED);

    u16 *hbuf, *Hfin_hi, *Hfin_lo;
    int* ep;
    float* ghd;
    u16 *eWhhH, *eWhhL, *dWhhH, *dWhhL;
    u16 *eWihH, *eWihL, *dWihH, *dWihL;
    u16 *pWH, *pWL;

    if (rot) {
        hbuf  = (u16*)(ws);                        // 129 x 1MB rotating h
        ep    = (int*)(ws + 135266304);            // 16 KB (sub-counters)
        ghd   = (float*)(ws + 135282688);          // 3 MB
        eWhhH = (u16*)(ws + 138428416);            // 6 MB each
        eWhhL = (u16*)(ws + 144719872);
        dWhhH = (u16*)(ws + 151011328);
        dWhhL = (u16*)(ws + 157302784);
        eWihH = (u16*)(ws + 163594240);            // 384 KB each
        eWihL = (u16*)(ws + 163987456);
        dWihH = (u16*)(ws + 164380672);
        dWihL = (u16*)(ws + 164773888);
        pWH   = (u16*)(ws + 165167104);            // 128 KB each
        pWL   = (u16*)(ws + 165298176);
        Hfin_hi = hbuf + (size_t)128 * 524288;     // buf[128] hi
        Hfin_lo = Hfin_hi + 262144;                // buf[128] lo
    } else {
        hbuf  = (u16*)(ws);                        // H0hi/H0lo/H1hi/H1lo (2 MB)
        ep    = (int*)(ws + 2097152);              // 256 epoch slots x 64 B
        ghd   = (float*)(ws + 3145728);            // 3 MB
        eWhhH = (u16*)(ws + 6291456);              // 6 MB each
        eWhhL = (u16*)(ws + 12582912);
        dWhhH = (u16*)(ws + 18874368);
        dWhhL = (u16*)(ws + 25165824);
        eWihH = (u16*)(ws + 31457280);             // 384 KB each (3072 x 64)
        eWihL = (u16*)(ws + 31850496);
        dWihH = (u16*)(ws + 32243712);
        dWihL = (u16*)(ws + 32636928);
        pWH   = (u16*)(ws + 33030144);             // 128 KB each (64 x 1024)
        pWL   = (u16*)(ws + 33161216);
        Hfin_hi = hbuf;                            // final enc_h in H0
        Hfin_lo = hbuf + 262144;
    }

    // one-time fp32 -> bf16 hi+lo weight conversions
    conv_split<<<dim3(4096), dim3(256), 0, stream>>>(eWhh, eWhhH, eWhhL, 3145728);
    conv_split<<<dim3(4096), dim3(256), 0, stream>>>(dWhh, dWhhH, dWhhL, 3145728);
    conv_wih_split_pad<<<dim3(768), dim3(256), 0, stream>>>(eWih, eWihH, eWihL);
    conv_wih_split_pad<<<dim3(768), dim3(256), 0, stream>>>(dWih, dWihH, dWihL);
    conv_pw_split_pad<<<dim3(256), dim3(256), 0, stream>>>(pW, pWH, pWL);

    if (rot) {
        // zero buf[0] (1 MB) + sub-counters (16 KB)
        zero_ws<<<dim3(256), dim3(256), 0, stream>>>((i4v*)hbuf, 65536);
        zero_ws<<<dim3(4), dim3(256), 0, stream>>>((i4v*)ep, 1024);
        enc_persist_reg<<<dim3(256), dim3(512), 0, stream>>>(
            eWhhH, eWhhL, eWihH, eWihL, ebih, ebhh, enc_x, hbuf, ep);
    } else {
        // zero h buffers (2 MB) + epoch slots (16 KB)
        zero_ws<<<dim3(517), dim3(256), 0, stream>>>((i4v*)ws, 132096);
        enc_persist_legacy<<<dim3(256), dim3(512), 0, stream>>>(
            eWhhH, eWhhL, eWihH, eWihL, ebih, ebhh, enc_x, hbuf, ep);
    }

    // gh_dec = enc_h @ dec_Whh^T + dec_bhh
    gru_gemm1<<<dim3(256), dim3(256), 0, stream>>>(
        dWhhH, dWhhL, dbhh, Hfin_hi, Hfin_lo, ghd);

    // fused decoder gates + projection -> fp32 out
    dec_fused<<<dim3(256), dim3(256), 0, stream>>>(
        dWihH, dWihL, dbih, dec_x, Hfin_hi, Hfin_lo, ghd, pWH, pWL, pb,
        (float*)d_out);
}

// Round 3
// 1520.340 us; speedup vs baseline: 1.7992x; 1.0219x over previous
//
#include <hip/hip_runtime.h>

// Seq2Seq GRU: B=256, S=128, T=64, I=63, H=1024. Inputs fp32, output fp32.
// All GEMMs: bf16 hi+lo 3-term split emulation (~fp32 accuracy).
// Encoder v8: persistent kernel, 128 steps, fence-free rotating buffers
//   (round-1-proven), register-resident Whh (round-2-proven). NEW:
//   - PER-WAVE decoupled waiting: wave w's K-slice [128w,128w+128) is
//     produced exactly by the 8 blocks with jt in [8w,8w+8) == sub-counter
//     (mt,w). Each wave polls ONE counter and proceeds independently;
//     waves only converge at the LDS reduce. (Skew<=1 induction unchanged:
//     a block posts s+1 only after all 8 of its waves saw all 8 counters
//     >= 8s, so ctr>=8s  =>  every block of that sub-group posted >= s.)
//   - gi (x @ Wih, h-independent) computed BEFORE the poll (wait shadow).
//   - h packed as u32 = hh | ll<<16: halves store packets (64B-coalesced
//     dword stores -> faster vmcnt drain before flag) and load count
//     (unpack = 6 VALU per 8 elems).
//   - No fp32->bf16 conv prologue for Whh: encoder splits eWhh fp32 in
//     registers at init; gru_gemm1 splits dWhh on the fly while staging
//     (same global bytes as reading two split planes).

typedef unsigned short u16;
typedef unsigned int   u32;
typedef __attribute__((ext_vector_type(8))) short s8v;   // 8 x bf16 (4 VGPRs)
typedef __attribute__((ext_vector_type(4))) float f4v;   // MFMA acc
typedef __attribute__((ext_vector_type(4))) int  i4v;    // 16B copy unit
typedef __attribute__((ext_vector_type(4))) unsigned int u4v;

__device__ __forceinline__ float b2f(u16 u) {
    return __uint_as_float(((u32)u) << 16);
}
__device__ __forceinline__ u16 f2b(float f) {   // round-to-nearest-even
    u32 x = __float_as_uint(f);
    u32 r = x + 0x7fffu + ((x >> 16) & 1u);
    return (u16)(r >> 16);
}
__device__ __forceinline__ float sigf(float x) {
    return 1.0f / (1.0f + __expf(-x));
}
__device__ __forceinline__ f4v mfma16(s8v a, s8v b, f4v c) {
    return __builtin_amdgcn_mfma_f32_16x16x32_bf16(a, b, c, 0, 0, 0);
}
// 8 packed u32 (hh|ll<<16) -> hi-plane s8v + lo-plane s8v
__device__ __forceinline__ void unpack8(u4v w0, u4v w1, s8v& hi, s8v& lo) {
    u32 c0 = w0[0], c1 = w0[1], c2 = w0[2], c3 = w0[3];
    u32 c4 = w1[0], c5 = w1[1], c6 = w1[2], c7 = w1[3];
    union { u32 u[4]; s8v v; } H, L;
    H.u[0] = (c0 & 0xffffu) | (c1 << 16);
    H.u[1] = (c2 & 0xffffu) | (c3 << 16);
    H.u[2] = (c4 & 0xffffu) | (c5 << 16);
    H.u[3] = (c6 & 0xffffu) | (c7 << 16);
    L.u[0] = (c0 >> 16) | (c1 & 0xffff0000u);
    L.u[1] = (c2 >> 16) | (c3 & 0xffff0000u);
    L.u[2] = (c4 >> 16) | (c5 & 0xffff0000u);
    L.u[3] = (c6 >> 16) | (c7 & 0xffff0000u);
    hi = H.v; lo = L.v;
}

// ---------------------------------------------------------------------------
__global__ void zero_ws(i4v* __restrict__ p, int n) {
    int i = blockIdx.x * blockDim.x + threadIdx.x;
    if (i < n) { i4v z = {0, 0, 0, 0}; p[i] = z; }
}

// Wih (3072 x 63 fp32) -> padded (3072 x 64) hi+lo, col 63 = 0
__global__ void conv_wih_split_pad(const float* __restrict__ s,
                                   u16* __restrict__ hi, u16* __restrict__ lo) {
    int idx = blockIdx.x * blockDim.x + threadIdx.x;
    int row = idx >> 6, col = idx & 63;
    float v = (col < 63) ? s[(size_t)row * 63 + col] : 0.f;
    u16 h = f2b(v);
    hi[idx] = h;
    lo[idx] = f2b(v - b2f(h));
}

// proj_W (63 x 1024 fp32) -> padded (64 x 1024) hi+lo, row 63 = 0
__global__ void conv_pw_split_pad(const float* __restrict__ s,
                                  u16* __restrict__ hi, u16* __restrict__ lo) {
    int idx = blockIdx.x * blockDim.x + threadIdx.x;
    float v = (idx < 63 * 1024) ? s[idx] : 0.f;
    u16 h = f2b(v);
    hi[idx] = h;
    lo[idx] = f2b(v - b2f(h));
}

// ---------------------------------------------------------------------------
// Persistent encoder v8.
__global__ __launch_bounds__(512, 1) void enc_persist8(
    const float* __restrict__ Whh,                 // fp32 3072 x 1024
    const u16* __restrict__ WihH, const u16* __restrict__ WihL,
    const float* __restrict__ bih, const float* __restrict__ bhh,
    const float* __restrict__ xenc,
    u32* __restrict__ hbuf,                        // 129 x (256x1024) packed
    int* __restrict__ ep)                          // 32 sub-counters x 64B
{
    __shared__ f4v red[8][4][3][64];   // 98.3 KB: per-wave k-slice partials
    __shared__ u16 WisH[48 * 72];      // Wih slice (persistent)
    __shared__ u16 WisL[48 * 72];

    // one-time: drop stale lines from a previous graph replay
    __builtin_amdgcn_fence(__ATOMIC_ACQUIRE, "agent");

    const int tid  = threadIdx.x;
    const int lane = tid & 63;
    const int wave = tid >> 6;          // 0..7 : k-slice owner, k0 = wave*128
    const int lrow = lane & 15;
    const int lk8  = lane >> 4;
    // XCD-aware swizzle: bid&7 = XCD; XCD owns a 128-col j-range.
    const int bid = blockIdx.x;
    const int xcd = bid & 7;
    const int y   = bid >> 3;
    const int mt  = y & 3;
    const int jt  = xcd * 8 + (y >> 2);
    const int m0 = mt * 64;
    const int j0 = jt * 16;

    // sub-counter (mt, xcd): incremented by its 8 blocks each step.
    int* subCtr  = ep + (mt * 8 + xcd) * 16;
    // wave w's producers (jt' in [8w,8w+8)) all live on XCD w -> ONE counter.
    int* waveCtr = ep + (mt * 8 + wave) * 16;

    // ---- one-time: Wih slice into LDS
    if (tid < 192) {
        int wr = tid >> 2, qq = tid & 3;
        int grow = (wr >> 4) * 1024 + j0 + (wr & 15);
        const u16* wpH = WihH + (size_t)grow * 64 + qq * 16;
        const u16* wpL = WihL + (size_t)grow * 64 + qq * 16;
        *(i4v*)&WisH[wr * 72 + qq * 16]     = *(const i4v*)wpH;
        *(i4v*)&WisH[wr * 72 + qq * 16 + 8] = *(const i4v*)(wpH + 8);
        *(i4v*)&WisL[wr * 72 + qq * 16]     = *(const i4v*)wpL;
        *(i4v*)&WisL[wr * 72 + qq * 16 + 8] = *(const i4v*)(wpL + 8);
    }

    // ---- one-time: this wave's Whh K-slice fp32 -> bf16 hi+lo in registers
    s8v bHf[3][4], bLf[3][4];
    const int k0 = wave * 128;
    #pragma unroll
    for (int gg = 0; gg < 3; ++gg)
        #pragma unroll
        for (int ks = 0; ks < 4; ++ks) {
            const float* p = Whh + (size_t)(gg * 1024 + j0 + lrow) * 1024 +
                             k0 + ks * 32 + lk8 * 8;
            f4v a = *(const f4v*)p;
            f4v b = *(const f4v*)(p + 4);
            union { u16 a[8]; s8v v; } H, L;
            #pragma unroll
            for (int j = 0; j < 8; ++j) {
                float v = (j < 4) ? a[j] : b[j - 4];
                u16 hh = f2b(v);
                H.a[j] = hh;
                L.a[j] = f2b(v - b2f(hh));
            }
            bHf[gg][ks] = H.v;
            bLf[gg][ks] = L.v;
        }

    const int jcol = j0 + lrow;
    const float bhr = bhh[jcol], bhz = bhh[1024 + jcol], bhn = bhh[2048 + jcol];
    const float bir = bih[jcol], biz = bih[1024 + jcol], bin = bih[2048 + jcol];

    // A-load element offsets per m-tile (u32 elements)
    size_t aoff[4];
    #pragma unroll
    for (int mtile = 0; mtile < 4; ++mtile)
        aoff[mtile] = (size_t)(m0 + mtile * 16 + lrow) * 1024 + k0 + lk8 * 8;

    // gi / epilogue waves: wave v (0..3) owns m-tile v
    const float* xrow = xenc + (size_t)(m0 + (wave & 3) * 16 + lrow) * 8064;
    float hprev[4] = {0.f, 0.f, 0.f, 0.f};

    float xf[16];
    if (wave < 4) {
        #pragma unroll
        for (int ks = 0; ks < 2; ++ks)
            #pragma unroll
            for (int j = 0; j < 8; ++j) {
                int col = ks * 32 + lk8 * 8 + j;
                xf[ks * 8 + j] = (col < 63) ? xrow[col] : 0.f;
            }
    }

    __syncthreads();   // Wis ready

    for (int s = 0; s < 128; ++s) {
        const u32* hin = hbuf + (size_t)s * 262144;        // read buf[s]
        u32* hout      = hbuf + (size_t)(s + 1) * 262144;  // write buf[s+1]

        // ---- gi (waves 0-3): h-independent -> compute in the wait shadow
        f4v gi_r = {0.f, 0.f, 0.f, 0.f};
        f4v gi_z = {0.f, 0.f, 0.f, 0.f};
        f4v gi_n = {0.f, 0.f, 0.f, 0.f};
        if (wave < 4) {
            #pragma unroll
            for (int ks = 0; ks < 2; ++ks) {
                union { u16 a[8]; s8v v; } xh, xl;
                #pragma unroll
                for (int j = 0; j < 8; ++j) {
                    float v = xf[ks * 8 + j];
                    u16 hh = f2b(v);
                    xh.a[j] = hh;
                    xl.a[j] = f2b(v - b2f(hh));
                }
                int ao = ks * 32 + lk8 * 8;
                s8v brh = *(const s8v*)&WisH[(lrow) * 72 + ao];
                s8v brl = *(const s8v*)&WisL[(lrow) * 72 + ao];
                s8v bzh = *(const s8v*)&WisH[(16 + lrow) * 72 + ao];
                s8v bzl = *(const s8v*)&WisL[(16 + lrow) * 72 + ao];
                s8v bnh = *(const s8v*)&WisH[(32 + lrow) * 72 + ao];
                s8v bnl = *(const s8v*)&WisL[(32 + lrow) * 72 + ao];
                gi_r = mfma16(xh.v, brh, gi_r);
                gi_r = mfma16(xh.v, brl, gi_r);
                gi_r = mfma16(xl.v, brh, gi_r);
                gi_z = mfma16(xh.v, bzh, gi_z);
                gi_z = mfma16(xh.v, bzl, gi_z);
                gi_z = mfma16(xl.v, bzh, gi_z);
                gi_n = mfma16(xh.v, bnh, gi_n);
                gi_n = mfma16(xh.v, bnl, gi_n);
                gi_n = mfma16(xl.v, bnh, gi_n);
            }
        }

        // ---- per-wave wait: only THIS wave's 8 producers (one counter).
        if (s) {
            const int tgt = s * 8;
            while (__hip_atomic_load(waveCtr, __ATOMIC_RELAXED,
                                     __HIP_MEMORY_SCOPE_SYSTEM) < tgt)
                __builtin_amdgcn_s_sleep(1);
        }

        // ---- K loop: 4 m-tiles x 4 ks, B in regs, packed-A unpack
        f4v accr[4], accz[4], acchn[4];
        #pragma unroll
        for (int m = 0; m < 4; ++m) {
            accr[m]  = f4v{0.f, 0.f, 0.f, 0.f};
            accz[m]  = f4v{0.f, 0.f, 0.f, 0.f};
            acchn[m] = f4v{0.f, 0.f, 0.f, 0.f};
        }
        #pragma unroll
        for (int mtile = 0; mtile < 4; ++mtile) {
            #pragma unroll
            for (int ks = 0; ks < 4; ++ks) {
                const u32* p = hin + aoff[mtile] + ks * 32;
                u4v w0 = *(const u4v*)p;
                u4v w1 = *(const u4v*)(p + 4);
                s8v ahi, alo;
                unpack8(w0, w1, ahi, alo);
                accr[mtile]  = mfma16(ahi, bHf[0][ks], accr[mtile]);
                accr[mtile]  = mfma16(ahi, bLf[0][ks], accr[mtile]);
                accr[mtile]  = mfma16(alo, bHf[0][ks], accr[mtile]);
                accz[mtile]  = mfma16(ahi, bHf[1][ks], accz[mtile]);
                accz[mtile]  = mfma16(ahi, bLf[1][ks], accz[mtile]);
                accz[mtile]  = mfma16(alo, bHf[1][ks], accz[mtile]);
                acchn[mtile] = mfma16(ahi, bHf[2][ks], acchn[mtile]);
                acchn[mtile] = mfma16(ahi, bLf[2][ks], acchn[mtile]);
                acchn[mtile] = mfma16(alo, bHf[2][ks], acchn[mtile]);
            }
        }

        // ---- write k-slice partials
        #pragma unroll
        for (int m = 0; m < 4; ++m) {
            red[wave][m][0][lane] = accr[m];
            red[wave][m][1][lane] = accz[m];
            red[wave][m][2][lane] = acchn[m];
        }
        __syncthreads();

        // ---- epilogue (waves 0-3): 8-way reduce, gates, packed h store
        if (wave < 4) {
            f4v sr = {0.f, 0.f, 0.f, 0.f};
            f4v sz = {0.f, 0.f, 0.f, 0.f};
            f4v sh = {0.f, 0.f, 0.f, 0.f};
            #pragma unroll
            for (int w = 0; w < 8; ++w) {
                sr += red[w][wave][0][lane];
                sz += red[w][wave][1][lane];
                sh += red[w][wave][2][lane];
            }
            #pragma unroll
            for (int reg = 0; reg < 4; ++reg) {
                int brow = m0 + wave * 16 + lk8 * 4 + reg;
                float rr = sigf(sr[reg] + gi_r[reg] + bir + bhr);
                float zz = sigf(sz[reg] + gi_z[reg] + biz + bhz);
                float nn = tanhf(gi_n[reg] + bin + rr * (sh[reg] + bhn));
                float h = (1.f - zz) * nn + zz * hprev[reg];
                u16 hh = f2b(h);
                u16 ll = f2b(h - b2f(hh));
                hprev[reg] = b2f(hh) + b2f(ll);
                u32 pk = (u32)hh | ((u32)ll << 16);
                // write-through (sc0 sc1): visible once vmcnt drains at the
                // barrier below -> no wbl2 needed.
                __hip_atomic_store(&hout[(size_t)brow * 1024 + jcol], pk,
                                   __ATOMIC_RELAXED, __HIP_MEMORY_SCOPE_SYSTEM);
            }
        }

        __syncthreads();   // drains h stores (vmcnt 0 per wave)
        if (tid == 0)
            __hip_atomic_fetch_add(subCtr, 1, __ATOMIC_RELAXED,
                                   __HIP_MEMORY_SCOPE_SYSTEM);
        // prefetch next step's x (immutable input)
        if (wave < 4) {
            int sn = (s < 127) ? s + 1 : 127;
            const float* xr = xrow + sn * 63;
            #pragma unroll
            for (int ks = 0; ks < 2; ++ks)
                #pragma unroll
                for (int j = 0; j < 8; ++j) {
                    int col = ks * 32 + lk8 * 8 + j;
                    xf[ks * 8 + j] = (col < 63) ? xr[col] : 0.f;
                }
        }
    }
}

// ---------------------------------------------------------------------------
// gh_dec = enc_h @ dec_Whh^T + dec_bhh (fp32 out). dWhh split on the fly.
__global__ __launch_bounds__(256, 1) void gru_gemm1(
    const float* __restrict__ Whh,                 // fp32 3072 x 1024
    const float* __restrict__ bhh,
    const u32* __restrict__ hin,                   // packed hh|ll<<16
    float* __restrict__ gh_out)
{
    __shared__ u16 WbH[48 * 264];
    __shared__ u16 WbL[48 * 264];

    const int tid  = threadIdx.x;
    const int lane = tid & 63;
    const int wave = tid >> 6;
    const int lrow = lane & 15;
    const int lk8  = lane >> 4;
    const int mt = blockIdx.x & 3;
    const int jt = blockIdx.x >> 2;
    const int m0 = mt * 64;
    const int j0 = jt * 16;

    f4v acc_r  = {0.f, 0.f, 0.f, 0.f};
    f4v acc_z  = {0.f, 0.f, 0.f, 0.f};
    f4v acc_hn = {0.f, 0.f, 0.f, 0.f};

    f4v stgA[6], stgB[6];
    #pragma unroll
    for (int i = 0; i < 6; ++i) {
        int c16 = i * 256 + tid;
        int row = c16 >> 5, p16 = c16 & 31;
        int grow = (row >> 4) * 1024 + j0 + (row & 15);
        const float* p = Whh + (size_t)grow * 1024 + p16 * 8;
        stgA[i] = *(const f4v*)p;
        stgB[i] = *(const f4v*)(p + 4);
    }
    #pragma unroll
    for (int i = 0; i < 6; ++i) {
        int c16 = i * 256 + tid;
        int row = c16 >> 5, p16 = c16 & 31;
        union { u16 a[8]; i4v v; } H, L;
        #pragma unroll
        for (int j = 0; j < 8; ++j) {
            float v = (j < 4) ? stgA[i][j] : stgB[i][j - 4];
            u16 hh = f2b(v);
            H.a[j] = hh;
            L.a[j] = f2b(v - b2f(hh));
        }
        *(i4v*)&WbH[row * 264 + p16 * 8] = H.v;
        *(i4v*)&WbL[row * 264 + p16 * 8] = L.v;
    }
    __syncthreads();

    const size_t arow = (size_t)(m0 + wave * 16 + lrow) * 1024 + lk8 * 8;
    const u32* hp = hin + arow;

    for (int c = 0; c < 4; ++c) {
        if (c < 3) {
            #pragma unroll
            for (int i = 0; i < 6; ++i) {
                int c16 = i * 256 + tid;
                int row = c16 >> 5, p16 = c16 & 31;
                int grow = (row >> 4) * 1024 + j0 + (row & 15);
                const float* p = Whh + (size_t)grow * 1024 + (c + 1) * 256 + p16 * 8;
                stgA[i] = *(const f4v*)p;
                stgB[i] = *(const f4v*)(p + 4);
            }
        }
        #pragma unroll
        for (int ks = 0; ks < 8; ++ks) {
            int kk = c * 256 + ks * 32;
            int bo = ks * 32 + lk8 * 8;
            u4v w0 = *(const u4v*)(hp + kk);
            u4v w1 = *(const u4v*)(hp + kk + 4);
            s8v ahi, alo;
            unpack8(w0, w1, ahi, alo);
            s8v brh = *(const s8v*)&WbH[(lrow) * 264 + bo];
            s8v brl = *(const s8v*)&WbL[(lrow) * 264 + bo];
            s8v bzh = *(const s8v*)&WbH[(16 + lrow) * 264 + bo];
            s8v bzl = *(const s8v*)&WbL[(16 + lrow) * 264 + bo];
            s8v bnh = *(const s8v*)&WbH[(32 + lrow) * 264 + bo];
            s8v bnl = *(const s8v*)&WbL[(32 + lrow) * 264 + bo];
            acc_r  = mfma16(ahi, brh, acc_r);
            acc_r  = mfma16(ahi, brl, acc_r);
            acc_r  = mfma16(alo, brh, acc_r);
            acc_z  = mfma16(ahi, bzh, acc_z);
            acc_z  = mfma16(ahi, bzl, acc_z);
            acc_z  = mfma16(alo, bzh, acc_z);
            acc_hn = mfma16(ahi, bnh, acc_hn);
            acc_hn = mfma16(ahi, bnl, acc_hn);
            acc_hn = mfma16(alo, bnh, acc_hn);
        }
        __syncthreads();
        if (c < 3) {
            #pragma unroll
            for (int i = 0; i < 6; ++i) {
                int c16 = i * 256 + tid;
                int row = c16 >> 5, p16 = c16 & 31;
                union { u16 a[8]; i4v v; } H, L;
                #pragma unroll
                for (int j = 0; j < 8; ++j) {
                    float v = (j < 4) ? stgA[i][j] : stgB[i][j - 4];
                    u16 hh = f2b(v);
                    H.a[j] = hh;
                    L.a[j] = f2b(v - b2f(hh));
                }
                *(i4v*)&WbH[row * 264 + p16 * 8] = H.v;
                *(i4v*)&WbL[row * 264 + p16 * 8] = L.v;
            }
            __syncthreads();
        }
    }

    const int jcol = j0 + lrow;
    const float bhr = bhh[jcol];
    const float bhz = bhh[1024 + jcol];
    const float bhn = bhh[2048 + jcol];
    #pragma unroll
    for (int reg = 0; reg < 4; ++reg) {
        int brow = m0 + wave * 16 + lk8 * 4 + reg;
        gh_out[(size_t)brow * 3072 + jcol]        = acc_r[reg] + bhr;
        gh_out[(size_t)brow * 3072 + 1024 + jcol] = acc_z[reg] + bhz;
        gh_out[(size_t)brow * 3072 + 2048 + jcol] = acc_hn[reg] + bhn;
    }
}

// ---------------------------------------------------------------------------
// Fused decoder (enc_h now packed u32)
__global__ __launch_bounds__(256, 1) void dec_fused(
    const u16* __restrict__ WihH, const u16* __restrict__ WihL,
    const float* __restrict__ bih,
    const float* __restrict__ xdec,
    const u32* __restrict__ e32,
    const float* __restrict__ gh,
    const u16* __restrict__ pWH, const u16* __restrict__ pWL,
    const float* __restrict__ pb,
    float* __restrict__ out)
{
    __shared__ u16 XdH[64 * 72];
    __shared__ u16 XdL[64 * 72];
    __shared__ u16 WiH_[192 * 72];
    __shared__ u16 WiL_[192 * 72];
    __shared__ u16 nsH[64 * 72];
    __shared__ u16 nsL[64 * 72];

    const int tid  = threadIdx.x;
    const int lane = tid & 63;
    const int wave = tid >> 6;
    const int lrow = lane & 15;
    const int lk8  = lane >> 4;
    const int b    = blockIdx.x;

    {
        int row = tid >> 2, q = tid & 3;
        const float* xr = xdec + (size_t)(b * 64 + row) * 63;
        #pragma unroll
        for (int ii = 0; ii < 16; ++ii) {
            int col = q * 16 + ii;
            float v = (col < 63) ? xr[col] : 0.f;
            u16 hh = f2b(v);
            XdH[row * 72 + col] = hh;
            XdL[row * 72 + col] = f2b(v - b2f(hh));
        }
    }

    f4v oacc[4];
    #pragma unroll
    for (int f = 0; f < 4; ++f) oacc[f] = f4v{0.f, 0.f, 0.f, 0.f};

    for (int j0 = 0; j0 < 1024; j0 += 64) {
        #pragma unroll
        for (int k = 0; k < 3; ++k) {
            int c = tid + k * 256;
            int r = c >> 2, qq = c & 3;
            int grow = (r >> 6) * 1024 + j0 + (r & 63);
            const u16* srcH = WihH + (size_t)grow * 64 + qq * 16;
            const u16* srcL = WihL + (size_t)grow * 64 + qq * 16;
            *(i4v*)&WiH_[r * 72 + qq * 16]     = *(const i4v*)srcH;
            *(i4v*)&WiH_[r * 72 + qq * 16 + 8] = *(const i4v*)(srcH + 8);
            *(i4v*)&WiL_[r * 72 + qq * 16]     = *(const i4v*)srcL;
            *(i4v*)&WiL_[r * 72 + qq * 16 + 8] = *(const i4v*)(srcL + 8);
        }
        __syncthreads();

        f4v ar[4], az[4], an[4];
        #pragma unroll
        for (int jf = 0; jf < 4; ++jf) {
            ar[jf] = f4v{0.f, 0.f, 0.f, 0.f};
            az[jf] = f4v{0.f, 0.f, 0.f, 0.f};
            an[jf] = f4v{0.f, 0.f, 0.f, 0.f};
        }
        #pragma unroll
        for (int ks = 0; ks < 2; ++ks) {
            int ao = ks * 32 + lk8 * 8;
            s8v ah = *(const s8v*)&XdH[(wave * 16 + lrow) * 72 + ao];
            s8v al = *(const s8v*)&XdL[(wave * 16 + lrow) * 72 + ao];
            #pragma unroll
            for (int jf = 0; jf < 4; ++jf) {
                s8v brh = *(const s8v*)&WiH_[(jf * 16 + lrow) * 72 + ao];
                s8v brl = *(const s8v*)&WiL_[(jf * 16 + lrow) * 72 + ao];
                s8v bzh = *(const s8v*)&WiH_[(64 + jf * 16 + lrow) * 72 + ao];
                s8v bzl = *(const s8v*)&WiL_[(64 + jf * 16 + lrow) * 72 + ao];
                s8v bnh = *(const s8v*)&WiH_[(128 + jf * 16 + lrow) * 72 + ao];
                s8v bnl = *(const s8v*)&WiL_[(128 + jf * 16 + lrow) * 72 + ao];
                ar[jf] = mfma16(ah, brh, ar[jf]);
                ar[jf] = mfma16(ah, brl, ar[jf]);
                ar[jf] = mfma16(al, brh, ar[jf]);
                az[jf] = mfma16(ah, bzh, az[jf]);
                az[jf] = mfma16(ah, bzl, az[jf]);
                az[jf] = mfma16(al, bzh, az[jf]);
                an[jf] = mfma16(ah, bnh, an[jf]);
                an[jf] = mfma16(ah, bnl, an[jf]);
                an[jf] = mfma16(al, bnh, an[jf]);
            }
        }

        #pragma unroll
        for (int jf = 0; jf < 4; ++jf) {
            int j = j0 + jf * 16 + lrow;
            float ghr = gh[(size_t)b * 3072 + j];
            float ghz = gh[(size_t)b * 3072 + 1024 + j];
            float ghn = gh[(size_t)b * 3072 + 2048 + j];
            float bir = bih[j];
            float biz = bih[1024 + j];
            float bin = bih[2048 + j];
            u32 pk = e32[(size_t)b * 1024 + j];
            float he = b2f((u16)(pk & 0xffffu)) + b2f((u16)(pk >> 16));
            #pragma unroll
            for (int reg = 0; reg < 4; ++reg) {
                float r  = sigf(ar[jf][reg] + bir + ghr);
                float z  = sigf(az[jf][reg] + biz + ghz);
                float nn = tanhf(an[jf][reg] + bin + r * ghn);
                float v  = (1.f - z) * nn + z * he;
                u16 hh = f2b(v);
                int lo_i = (wave * 16 + lk8 * 4 + reg) * 72 + jf * 16 + lrow;
                nsH[lo_i] = hh;
                nsL[lo_i] = f2b(v - b2f(hh));
            }
        }
        __syncthreads();

        #pragma unroll
        for (int ks = 0; ks < 2; ++ks) {
            int ao = ks * 32 + lk8 * 8;
            s8v ah = *(const s8v*)&nsH[(wave * 16 + lrow) * 72 + ao];
            s8v al = *(const s8v*)&nsL[(wave * 16 + lrow) * 72 + ao];
            #pragma unroll
            for (int f = 0; f < 4; ++f) {
                size_t bo = (size_t)(f * 16 + lrow) * 1024 + j0 + ks * 32 + lk8 * 8;
                s8v bh = *(const s8v*)(pWH + bo);
                s8v bl = *(const s8v*)(pWL + bo);
                oacc[f] = mfma16(ah, bh, oacc[f]);
                oacc[f] = mfma16(ah, bl, oacc[f]);
                oacc[f] = mfma16(al, bh, oacc[f]);
            }
        }
        __syncthreads();
    }

    #pragma unroll
    for (int f = 0; f < 4; ++f) {
        int o = f * 16 + lrow;
        if (o < 63) {
            float pbv = pb[o];
            #pragma unroll
            for (int reg = 0; reg < 4; ++reg) {
                int t = wave * 16 + lk8 * 4 + reg;
                out[((size_t)(b * 64 + t)) * 63 + o] = oacc[f][reg] + pbv;
            }
        }
    }
}

// ---------------------------------------------------------------------------
extern "C" void kernel_launch(void* const* d_in, const int* in_sizes, int n_in,
                              void* d_out, int out_size, void* d_ws, size_t ws_size,
                              hipStream_t stream)
{
    const float* enc_x = (const float*)d_in[0];
    const float* dec_x = (const float*)d_in[1];
    const float* eWih  = (const float*)d_in[2];
    const float* eWhh  = (const float*)d_in[3];
    const float* ebih  = (const float*)d_in[4];
    const float* ebhh  = (const float*)d_in[5];
    const float* dWih  = (const float*)d_in[6];
    const float* dWhh  = (const float*)d_in[7];
    const float* dbih  = (const float*)d_in[8];
    const float* dbhh  = (const float*)d_in[9];
    const float* pW    = (const float*)d_in[10];
    const float* pb    = (const float*)d_in[11];

    char* ws = (char*)d_ws;

    // layout: 129MB hbuf(packed) + 16KB ep + 3MB ghd + 4x384KB Wih + 2x128KB pW
    u32*   hbuf  = (u32*)(ws);                     // 129 x 1MB rotating packed h
    int*   ep    = (int*)(ws + 135266304);         // 16 KB sub-counters
    float* ghd   = (float*)(ws + 135282688);       // 3 MB
    u16*   eWihH = (u16*)(ws + 138428416);         // 384 KB each
    u16*   eWihL = (u16*)(ws + 138821632);
    u16*   dWihH = (u16*)(ws + 139214848);
    u16*   dWihL = (u16*)(ws + 139608064);
    u16*   pWH   = (u16*)(ws + 140001280);         // 128 KB each
    u16*   pWL   = (u16*)(ws + 140132352);

    // small one-time conversions (Wih pad + proj pad); Whh splits are in-kernel
    conv_wih_split_pad<<<dim3(768), dim3(256), 0, stream>>>(eWih, eWihH, eWihL);
    conv_wih_split_pad<<<dim3(768), dim3(256), 0, stream>>>(dWih, dWihH, dWihL);
    conv_pw_split_pad<<<dim3(256), dim3(256), 0, stream>>>(pW, pWH, pWL);

    // zero buf[0] (1 MB packed) + sub-counters (16 KB)
    zero_ws<<<dim3(256), dim3(256), 0, stream>>>((i4v*)hbuf, 65536);
    zero_ws<<<dim3(4), dim3(256), 0, stream>>>((i4v*)ep, 1024);

    // persistent encoder: all 128 steps, one launch
    enc_persist8<<<dim3(256), dim3(512), 0, stream>>>(
        eWhh, eWihH, eWihL, ebih, ebhh, enc_x, hbuf, ep);

    u32* Hfin = hbuf + (size_t)128 * 262144;       // buf[128]

    // gh_dec = enc_h @ dec_Whh^T + dec_bhh (dWhh split on the fly)
    gru_gemm1<<<dim3(256), dim3(256), 0, stream>>>(dWhh, dbhh, Hfin, ghd);

    // fused decoder gates + projection -> fp32 out
    dec_fused<<<dim3(256), dim3(256), 0, stream>>>(
        dWihH, dWihL, dbih, dec_x, Hfin, ghd, pWH, pWL, pb, (float*)d_out);
}